// Round 1
// baseline (1505.125 us; speedup 1.0000x reference)
//
#include <hip/hip_runtime.h>

// ---------------------------------------------------------------------------
// HyperFNS: Helmholtz Jacobi + FNS spectral correction, B=8, N=256, K=3.
// All FFTs collapsed analytically into small sine/DFT matrix products.
// ---------------------------------------------------------------------------

#define BB 8
#define NSZ 256
#define NN 65536          // 256*256
#define MSZ 257
#define MM 66049          // 257*257

constexpr double PI_D    = 3.14159265358979323846;
constexpr double OMEGA_D = 40.0 * PI_D;           // N=256 -> omega = 40*pi
constexpr double H_D     = 1.0 / 255.0;
constexpr float  OMEGA2F = (float)(OMEGA_D * OMEGA_D);
constexpr float  BCVF    = (float)(2.0 * H_D * OMEGA_D);   // bc = i*BCVF
constexpr float  INVH2F  = 65025.0f;                        // 1/h^2 = 255^2
constexpr float  C1F     = (float)(-4.0 / (514.0 * 514.0)); // ifft2 odd-sym factor
constexpr float  TP514   = (float)(2.0 * PI_D / 514.0);

// --------------------------- init: kappa2, dinv, x=0, acc=0 -----------------
__global__ void k_init(const float* __restrict__ kappa, float* __restrict__ kap2,
                       float* __restrict__ dinv, float* __restrict__ x0,
                       float* __restrict__ acc) {
    int t = blockIdx.x * 256 + threadIdx.x;
    if (t < BB * NN) {
        float k = kappa[t];
        float k2 = k * k;
        kap2[t] = k2;
        dinv[t] = 1.0f / (4.0f * INVH2F - OMEGA2F * k2);
        x0[2 * t] = 0.f; x0[2 * t + 1] = 0.f;
    }
    if (t < 16) acc[t] = 0.f;
}

// --------------------------- transform matrices -----------------------------
// S [u<257][m<256]  = sin(2*pi*(u-128)*(m+1)/514)
// ST[p<256][v<257]  = S[v][p]
// W [k<256][u<257]  = (-1)^k * exp(-2*pi*i*k*(u+129)/514)
// WT[v<257][l<256]  = W[l][v]
__global__ void k_mats(float* __restrict__ S, float* __restrict__ ST,
                       float* __restrict__ W, float* __restrict__ WT) {
    int t = blockIdx.x * 256 + threadIdx.x;
    if (t >= MSZ * MSZ) return;
    int i = t / 257, j = t % 257;
    if (j < 256) {
        int a = (i - 128) * (j + 1);
        int m = ((a % 514) + 514) % 514;
        S[i * 256 + j] = sinf(m * TP514);
    }
    if (i < 256) {
        int a = (j - 128) * (i + 1);
        int m = ((a % 514) + 514) % 514;
        ST[i * 257 + j] = sinf(m * TP514);
        int tt = (i * (j + 129)) % 514;
        float cc = cosf(tt * TP514), ss = sinf(tt * TP514);
        float sg = (i & 1) ? -1.f : 1.f;
        W[(i * 257 + j) * 2] = sg * cc;
        W[(i * 257 + j) * 2 + 1] = -sg * ss;
    }
    if (j < 256) {
        int tt = (j * (i + 129)) % 514;
        float cc = cosf(tt * TP514), ss = sinf(tt * TP514);
        float sg = (j & 1) ? -1.f : 1.f;
        WT[(i * 256 + j) * 2] = sg * cc;
        WT[(i * 256 + j) * 2 + 1] = -sg * ss;
    }
}

// --------------------------- stencil: smooth / residual ---------------------
// mode 0: out = x + (2/3)*dinv*(f - A x);  mode 1: out = f - A x
__global__ void k_step(const float* __restrict__ xin, float* __restrict__ out,
                       const float* __restrict__ fr, const float* __restrict__ fi,
                       const float* __restrict__ kap2, const float* __restrict__ dinv,
                       int mode) {
    int t = blockIdx.x * 256 + threadIdx.x;
    if (t >= BB * NN) return;
    int b = t >> 16;
    int ij = t & 65535;
    int i = ij >> 8, j = ij & 255;
    const float* xb = xin + (size_t)b * NN * 2;
    float xcr = xb[2 * ij], xci = xb[2 * ij + 1];
    float ur, ui, dr, di, lr, li, rr, ri;
    if (i > 0) { int n = ij - 256; ur = xb[2 * n]; ui = xb[2 * n + 1]; }
    else { int n = 256 + j; ur = xb[2 * n] - BCVF * xci; ui = xb[2 * n + 1] + BCVF * xcr; }
    if (i < 255) { int n = ij + 256; dr = xb[2 * n]; di = xb[2 * n + 1]; }
    else { int n = 254 * 256 + j; dr = xb[2 * n] - BCVF * xci; di = xb[2 * n + 1] + BCVF * xcr; }
    if (j > 0) { int n = ij - 1; lr = xb[2 * n]; li = xb[2 * n + 1]; }
    else { int n = i * 256 + 1; lr = xb[2 * n] - BCVF * xci; li = xb[2 * n + 1] + BCVF * xcr; }
    if (j < 255) { int n = ij + 1; rr = xb[2 * n]; ri = xb[2 * n + 1]; }
    else { int n = i * 256 + 254; rr = xb[2 * n] - BCVF * xci; ri = xb[2 * n + 1] + BCVF * xcr; }
    float k2 = kap2[t];
    float axr = (4.f * xcr - ur - dr - lr - rr) * INVH2F - OMEGA2F * k2 * xcr;
    float axi = (4.f * xci - ui - di - li - ri) * INVH2F - OMEGA2F * k2 * xci;
    float resr = fr[t] - axr, resi = fi[t] - axi;
    if (mode == 0) {
        float dv = dinv[t] * (2.0f / 3.0f);
        out[2 * t] = xcr + dv * resr;
        out[2 * t + 1] = xci + dv * resi;
    } else {
        out[2 * t] = resr;
        out[2 * t + 1] = resi;
    }
}

// --------------------------- DST pass 1: tA[b][u][p] = sum_m S[u][m]*r[b][m][p]
__global__ void k_dst1(const float* __restrict__ r, const float* __restrict__ S,
                       float* __restrict__ tA) {
    int u = blockIdx.x, b = blockIdx.y, p = threadIdx.x;
    const float* rp = r + (size_t)b * NN * 2;
    const float* Su = S + u * 256;
    float ar = 0.f, ai = 0.f;
#pragma unroll 4
    for (int m = 0; m < 256; m++) {
        float s = Su[m];
        ar += s * rp[2 * (m * 256 + p)];
        ai += s * rp[2 * (m * 256 + p) + 1];
    }
    size_t o = ((size_t)(b * 257 + u) * 256 + p) * 2;
    tA[o] = ar; tA[o + 1] = ai;
}

// --------------------------- DST pass 2: tB[b][u][v] = C1*sum_p tA[u][p]*S[v][p]
__global__ void k_dst2(const float* __restrict__ tA, const float* __restrict__ ST,
                       float* __restrict__ tB) {
    int u = blockIdx.x, b = blockIdx.y;
    const float* ap = tA + (size_t)(b * 257 + u) * 256 * 2;
    for (int v = threadIdx.x; v < 257; v += 256) {
        float ar = 0.f, ai = 0.f;
#pragma unroll 4
        for (int p = 0; p < 256; p++) {
            float s = ST[p * 257 + v];
            ar += s * ap[2 * p];
            ai += s * ap[2 * p + 1];
        }
        size_t o = ((size_t)b * MM + u * 257 + v) * 2;
        tB[o] = C1F * ar; tB[o + 1] = C1F * ai;
    }
}

// --------------------------- complex 3x3 conv (per-batch weights) -----------
// forward: w[b][o][i][p][q];  adjoint: conj(w[b][i][o][q][p])
__global__ void k_conv(const float* __restrict__ in, float* __restrict__ out,
                       const float* __restrict__ wre, const float* __restrict__ wim,
                       int Cin, int Cout, int adj) {
    int b = blockIdx.z, o = blockIdx.y;
    __shared__ float ws_r[36], ws_i[36];
    int tid = threadIdx.x;
    if (tid < Cin * 9) {
        int ci = tid / 9, k = tid % 9, p = k / 3, q = k % 3;
        int widx; float sg;
        if (!adj) { widx = ((b * Cout + o) * Cin + ci) * 9 + p * 3 + q; sg = 1.f; }
        else      { widx = ((b * Cin + ci) * Cout + o) * 9 + q * 3 + p; sg = -1.f; }
        ws_r[tid] = wre[widx];
        ws_i[tid] = sg * wim[widx];
    }
    __syncthreads();
    int pix = blockIdx.x * blockDim.x + tid;
    if (pix >= MM) return;
    int y = pix / 257, x = pix % 257;
    float ar = 0.f, ai = 0.f;
    for (int ci = 0; ci < Cin; ci++) {
        const float* ip = in + (size_t)(b * Cin + ci) * MM * 2;
        for (int p = 0; p < 3; p++) {
            int yy = y + p - 1;
            if (yy < 0 || yy >= 257) continue;
            for (int q = 0; q < 3; q++) {
                int xx = x + q - 1;
                if (xx < 0 || xx >= 257) continue;
                float vr = ip[2 * (yy * 257 + xx)], vi = ip[2 * (yy * 257 + xx) + 1];
                float wr = ws_r[ci * 9 + p * 3 + q], wi = ws_i[ci * 9 + p * 3 + q];
                ar += vr * wr - vi * wi;
                ai += vr * wi + vi * wr;
            }
        }
    }
    size_t oo = ((size_t)(b * Cout + o) * MM + pix) * 2;
    out[oo] = ar; out[oo + 1] = ai;
}

// --------------------------- elementwise wt multiply ------------------------
__global__ void k_wtmul(const float* __restrict__ in, const float* __restrict__ wtr,
                        const float* __restrict__ wti, float* __restrict__ out) {
    int t = blockIdx.x * 256 + threadIdx.x;
    if (t >= BB * MM) return;
    float ar = in[2 * t], ai = in[2 * t + 1];
    float wr = wtr[t], wi = wti[t];
    out[2 * t] = ar * wr - ai * wi;
    out[2 * t + 1] = ar * wi + ai * wr;
}

// --------------------------- final DFT pass 1: tB[b][k][v] = sum_u W[k][u]*in[b][u][v]
__global__ void k_dft1(const float* __restrict__ in, const float* __restrict__ W,
                       float* __restrict__ tB) {
    int k = blockIdx.x, b = blockIdx.y;
    const float* ip = in + (size_t)b * MM * 2;
    const float* Wk = W + k * 257 * 2;
    for (int v = threadIdx.x; v < 257; v += 256) {
        float ar = 0.f, ai = 0.f;
        for (int u = 0; u < 257; u++) {
            float wr = Wk[2 * u], wi = Wk[2 * u + 1];
            float xr = ip[2 * (u * 257 + v)], xi = ip[2 * (u * 257 + v) + 1];
            ar += wr * xr - wi * xi;
            ai += wr * xi + wi * xr;
        }
        size_t o = ((size_t)b * MM + k * 257 + v) * 2;
        tB[o] = ar; tB[o + 1] = ai;
    }
}

// --------------------------- final DFT pass 2 + add into x ------------------
__global__ void k_dft2add(const float* __restrict__ tB, const float* __restrict__ WT,
                          float* __restrict__ x) {
    int k = blockIdx.x, b = blockIdx.y, l = threadIdx.x;
    const float* gp = tB + ((size_t)b * MM + k * 257) * 2;
    float ar = 0.f, ai = 0.f;
    for (int v = 0; v < 257; v++) {
        float gr = gp[2 * v], gi = gp[2 * v + 1];
        float wr = WT[(v * 256 + l) * 2], wi = WT[(v * 256 + l) * 2 + 1];
        ar += gr * wr - gi * wi;
        ai += gr * wi + gi * wr;
    }
    size_t o = ((size_t)b * NN + k * 256 + l) * 2;
    x[o] += ar; x[o + 1] += ai;
}

// --------------------------- norm reduction ---------------------------------
__global__ void k_reduce(const float* __restrict__ r, const float* __restrict__ fr,
                         const float* __restrict__ fi, float* __restrict__ acc) {
    int b = blockIdx.y;
    int tid = threadIdx.x;
    float sr = 0.f, sf = 0.f;
    for (int idx = blockIdx.x * 256 + tid; idx < NN; idx += gridDim.x * 256) {
        const float* rp = r + ((size_t)b * NN + idx) * 2;
        float rx = rp[0], ry = rp[1];
        sr += rx * rx + ry * ry;
        float a = fr[(size_t)b * NN + idx], c = fi[(size_t)b * NN + idx];
        sf += a * a + c * c;
    }
    for (int off = 32; off > 0; off >>= 1) {
        sr += __shfl_down(sr, off);
        sf += __shfl_down(sf, off);
    }
    __shared__ float ssr[4], ssf[4];
    int wid = tid >> 6, lane = tid & 63;
    if (lane == 0) { ssr[wid] = sr; ssf[wid] = sf; }
    __syncthreads();
    if (tid == 0) {
        float tr = ssr[0] + ssr[1] + ssr[2] + ssr[3];
        float tf = ssf[0] + ssf[1] + ssf[2] + ssf[3];
        atomicAdd(&acc[2 * b], tr);
        atomicAdd(&acc[2 * b + 1], tf);
    }
}

__global__ void k_finalize(const float* __restrict__ acc, float* __restrict__ out) {
    if (threadIdx.x == 0 && blockIdx.x == 0) {
        float num = 0.f, den = 0.f;
        for (int b = 0; b < BB; b++) {
            num += sqrtf(acc[2 * b]);
            den += sqrtf(acc[2 * b + 1]);
        }
        out[0] = num / den;
    }
}

// ---------------------------------------------------------------------------
extern "C" void kernel_launch(void* const* d_in, const int* in_sizes, int n_in,
                              void* d_out, int out_size, void* d_ws, size_t ws_size,
                              hipStream_t stream) {
    (void)in_sizes; (void)n_in; (void)out_size; (void)ws_size;
    const float* fr  = (const float*)d_in[0];
    const float* fi  = (const float*)d_in[1];
    const float* kap = (const float*)d_in[2];
    const float* w1r = (const float*)d_in[3];
    const float* w1i = (const float*)d_in[4];
    const float* w2r = (const float*)d_in[5];
    const float* w2i = (const float*)d_in[6];
    const float* w3r = (const float*)d_in[7];
    const float* w3i = (const float*)d_in[8];
    const float* wtr = (const float*)d_in[9];
    const float* wti = (const float*)d_in[10];
    // epoch = 81 -> K = (81-1)/40 + 1 = 3 (fixed by harness inputs)
    const int K = 3;

    float* ws = (float*)d_ws;
    size_t off = 0;
    float* x0   = ws + off; off += (size_t)BB * NN * 2;
    float* x1   = ws + off; off += (size_t)BB * NN * 2;
    float* rb   = ws + off; off += (size_t)BB * NN * 2;
    float* kap2 = ws + off; off += (size_t)BB * NN;
    float* dinv = ws + off; off += (size_t)BB * NN;
    float* tA   = ws + off; off += (size_t)BB * MM * 2;
    float* tB   = ws + off; off += (size_t)BB * MM * 2;
    float* c4a  = ws + off; off += (size_t)BB * 4 * MM * 2;
    float* c4b  = ws + off; off += (size_t)BB * 4 * MM * 2;
    float* S    = ws + off; off += 257 * 256;
    float* ST   = ws + off; off += 256 * 257;
    float* W    = ws + off; off += 256 * 257 * 2;
    float* WT   = ws + off; off += 257 * 256 * 2;
    float* acc  = ws + off; off += 16;

    int sgrid = (BB * NN + 255) / 256;
    k_init<<<sgrid, 256, 0, stream>>>(kap, kap2, dinv, x0, acc);
    k_mats<<<(MSZ * MSZ + 255) / 256, 256, 0, stream>>>(S, ST, W, WT);

    float* xc = x0;
    float* xo = x1;
    for (int it = 0; it < K; ++it) {
        for (int s = 0; s < 3; ++s) {
            k_step<<<sgrid, 256, 0, stream>>>(xc, xo, fr, fi, kap2, dinv, 0);
            float* t = xc; xc = xo; xo = t;
        }
        k_step<<<sgrid, 256, 0, stream>>>(xc, rb, fr, fi, kap2, dinv, 1);
        k_dst1<<<dim3(257, BB), 256, 0, stream>>>(rb, S, tA);
        k_dst2<<<dim3(257, BB), 256, 0, stream>>>(tA, ST, tB);
        k_conv<<<dim3(259, 4, BB), 256, 0, stream>>>(tB, c4a, w1r, w1i, 1, 4, 0);
        k_conv<<<dim3(259, 4, BB), 256, 0, stream>>>(c4a, c4b, w2r, w2i, 4, 4, 0);
        k_conv<<<dim3(259, 1, BB), 256, 0, stream>>>(c4b, tA, w3r, w3i, 4, 1, 0);
        k_wtmul<<<(BB * MM + 255) / 256, 256, 0, stream>>>(tA, wtr, wti, tB);
        k_conv<<<dim3(259, 4, BB), 256, 0, stream>>>(tB, c4a, w3r, w3i, 1, 4, 1);
        k_conv<<<dim3(259, 4, BB), 256, 0, stream>>>(c4a, c4b, w2r, w2i, 4, 4, 1);
        k_conv<<<dim3(259, 1, BB), 256, 0, stream>>>(c4b, tA, w1r, w1i, 4, 1, 1);
        k_dft1<<<dim3(256, BB), 256, 0, stream>>>(tA, W, tB);
        k_dft2add<<<dim3(256, BB), 256, 0, stream>>>(tB, WT, xc);
    }
    k_step<<<sgrid, 256, 0, stream>>>(xc, rb, fr, fi, kap2, dinv, 1);
    k_reduce<<<dim3(32, BB), 256, 0, stream>>>(rb, fr, fi, acc);
    k_finalize<<<1, 64, 0, stream>>>(acc, (float*)d_out);
}

// Round 2
// 1439.221 us; speedup vs baseline: 1.0458x; 1.0458x over previous
//
#include <hip/hip_runtime.h>

// ---------------------------------------------------------------------------
// HyperFNS: Helmholtz Jacobi + FNS spectral correction, B=8, N=256, K=3.
// FFTs collapsed analytically into sine/DFT matrix products, executed as
// LDS-tiled complex GEMMs. Convs register-block all output channels.
// ---------------------------------------------------------------------------

#define BB 8
#define NSZ 256
#define NN 65536          // 256*256
#define MSZ 257
#define MM 66049          // 257*257

constexpr double PI_D    = 3.14159265358979323846;
constexpr double OMEGA_D = 40.0 * PI_D;           // N=256 -> omega = 40*pi
constexpr double H_D     = 1.0 / 255.0;
constexpr float  OMEGA2F = (float)(OMEGA_D * OMEGA_D);
constexpr float  BCVF    = (float)(2.0 * H_D * OMEGA_D);   // bc = i*BCVF
constexpr float  INVH2F  = 65025.0f;                        // 1/h^2 = 255^2
constexpr float  C1F     = (float)(-4.0 / (514.0 * 514.0)); // ifft2 odd-sym factor
constexpr float  TP514   = (float)(2.0 * PI_D / 514.0);

// --------------------------- init: kappa2, dinv, x=0, acc=0 -----------------
__global__ void k_init(const float* __restrict__ kappa, float* __restrict__ kap2,
                       float* __restrict__ dinv, float* __restrict__ x0,
                       float* __restrict__ acc) {
    int t = blockIdx.x * 256 + threadIdx.x;
    if (t < BB * NN) {
        float k = kappa[t];
        float k2 = k * k;
        kap2[t] = k2;
        dinv[t] = 1.0f / (4.0f * INVH2F - OMEGA2F * k2);
        x0[2 * t] = 0.f; x0[2 * t + 1] = 0.f;
    }
    if (t < 16) acc[t] = 0.f;
}

// --------------------------- transform matrices -----------------------------
// S [u<257][m<256]  = sin(2*pi*(u-128)*(m+1)/514)
// W [k<256][u<257]  = (-1)^k * exp(-2*pi*i*k*(u+129)/514)
// WT[v<257][l<256]  = W[l][v]
__global__ void k_mats(float* __restrict__ S, float* __restrict__ W,
                       float* __restrict__ WT) {
    int t = blockIdx.x * 256 + threadIdx.x;
    if (t >= MSZ * MSZ) return;
    int i = t / 257, j = t % 257;
    if (j < 256) {
        int a = (i - 128) * (j + 1);
        int m = ((a % 514) + 514) % 514;
        S[i * 256 + j] = sinf(m * TP514);
    }
    if (i < 256) {
        int tt = (i * (j + 129)) % 514;
        float cc = cosf(tt * TP514), ss = sinf(tt * TP514);
        float sg = (i & 1) ? -1.f : 1.f;
        W[(i * 257 + j) * 2] = sg * cc;
        W[(i * 257 + j) * 2 + 1] = -sg * ss;
    }
    if (j < 256) {
        int tt = (j * (i + 129)) % 514;
        float cc = cosf(tt * TP514), ss = sinf(tt * TP514);
        float sg = (j & 1) ? -1.f : 1.f;
        WT[(i * 256 + j) * 2] = sg * cc;
        WT[(i * 256 + j) * 2 + 1] = -sg * ss;
    }
}

// --------------------------- stencil: smooth / residual ---------------------
__global__ void k_step(const float* __restrict__ xin, float* __restrict__ out,
                       const float* __restrict__ fr, const float* __restrict__ fi,
                       const float* __restrict__ kap2, const float* __restrict__ dinv,
                       int mode) {
    int t = blockIdx.x * 256 + threadIdx.x;
    if (t >= BB * NN) return;
    int b = t >> 16;
    int ij = t & 65535;
    int i = ij >> 8, j = ij & 255;
    const float* xb = xin + (size_t)b * NN * 2;
    float xcr = xb[2 * ij], xci = xb[2 * ij + 1];
    float ur, ui, dr, di, lr, li, rr, ri;
    if (i > 0) { int n = ij - 256; ur = xb[2 * n]; ui = xb[2 * n + 1]; }
    else { int n = 256 + j; ur = xb[2 * n] - BCVF * xci; ui = xb[2 * n + 1] + BCVF * xcr; }
    if (i < 255) { int n = ij + 256; dr = xb[2 * n]; di = xb[2 * n + 1]; }
    else { int n = 254 * 256 + j; dr = xb[2 * n] - BCVF * xci; di = xb[2 * n + 1] + BCVF * xcr; }
    if (j > 0) { int n = ij - 1; lr = xb[2 * n]; li = xb[2 * n + 1]; }
    else { int n = i * 256 + 1; lr = xb[2 * n] - BCVF * xci; li = xb[2 * n + 1] + BCVF * xcr; }
    if (j < 255) { int n = ij + 1; rr = xb[2 * n]; ri = xb[2 * n + 1]; }
    else { int n = i * 256 + 254; rr = xb[2 * n] - BCVF * xci; ri = xb[2 * n + 1] + BCVF * xcr; }
    float k2 = kap2[t];
    float axr = (4.f * xcr - ur - dr - lr - rr) * INVH2F - OMEGA2F * k2 * xcr;
    float axi = (4.f * xci - ui - di - li - ri) * INVH2F - OMEGA2F * k2 * xci;
    float resr = fr[t] - axr, resi = fi[t] - axi;
    if (mode == 0) {
        float dv = dinv[t] * (2.0f / 3.0f);
        out[2 * t] = xcr + dv * resr;
        out[2 * t + 1] = xci + dv * resi;
    } else {
        out[2 * t] = resr;
        out[2 * t + 1] = resi;
    }
}

// --------------------------- tiled complex GEMM -----------------------------
// C[m][n] (+)= scale * sum_k A[m][k] * B[k][n]
// AREAL : A is real float matrix (lda in floats)
// BREALT: B is real and transposed: B[k][n] = Bg[n*ldb + k]
// CADD  : accumulate into C instead of overwrite
// Tiles: BM=32 x BN=64 x BK=16, 256 threads, per-thread 2x4 complex acc.
template<int AREAL, int BREALT, int CADD>
__global__ __launch_bounds__(256) void cgemm(
        const float* __restrict__ A, const float* __restrict__ Bg,
        float* __restrict__ C, int M, int N, int K,
        int lda, int ldb, int ldc,
        long aBatch, long bBatch, long cBatch, float scale) {
    constexpr int BM = 32, BN = 64, BK = 16;
    constexpr int LA = AREAL ? (BM + 1) : (BM + 2);   // row stride (elems)
    constexpr int LB = BREALT ? (BN + 1) : (BN + 2);
    __shared__ float shA[AREAL ? BK * LA : BK * LA * 2];
    __shared__ float shB[BREALT ? BK * LB : BK * LB * 2];

    const int tid = threadIdx.x;
    const int bz = blockIdx.z;
    const float* Ab = A + (size_t)bz * aBatch;
    const float* Bb = Bg + (size_t)bz * bBatch;
    float* Cb = C + (size_t)bz * cBatch;

    const int m0 = blockIdx.y * BM;
    const int n0 = blockIdx.x * BN;

    // A-load mapping: 32 rows x 16 k, 2 consecutive k per thread
    const int am = tid >> 3;
    const int ak = (tid & 7) * 2;
    // B-load mapping
    const int bk_n = tid >> 4;          // !BREALT: k row 0..15
    const int bn_n = (tid & 15) * 4;    // !BREALT: 4 consecutive n
    const int bn_t = tid >> 2;          // BREALT: n 0..63
    const int bk_t = (tid & 3) * 4;     // BREALT: 4 consecutive k

    const int ty = tid >> 4;   // 0..15 -> 2 m each
    const int tx = tid & 15;   // 0..15 -> 4 n each

    float acc[2][4][2];
#pragma unroll
    for (int i = 0; i < 2; i++)
#pragma unroll
        for (int j = 0; j < 4; j++) { acc[i][j][0] = 0.f; acc[i][j][1] = 0.f; }

    const int nkt = (K + BK - 1) / BK;
    for (int kt = 0; kt < nkt; kt++) {
        const int kb = kt * BK;
        // ---- load A tile ----
        {
            int gm = m0 + am;
#pragma unroll
            for (int s = 0; s < 2; s++) {
                int gk = kb + ak + s;
                if (AREAL) {
                    float v = (gm < M && gk < K) ? Ab[(size_t)gm * lda + gk] : 0.f;
                    shA[(ak + s) * LA + am] = v;
                } else {
                    float2 v = make_float2(0.f, 0.f);
                    if (gm < M && gk < K) v = ((const float2*)Ab)[(size_t)gm * lda + gk];
                    ((float2*)shA)[(ak + s) * LA + am] = v;
                }
            }
        }
        // ---- load B tile ----
        if (BREALT) {
            int gn = n0 + bn_t;
#pragma unroll
            for (int s = 0; s < 4; s++) {
                int gk = kb + bk_t + s;
                float v = (gk < K && gn < N) ? Bb[(size_t)gn * ldb + gk] : 0.f;
                shB[(bk_t + s) * LB + bn_t] = v;
            }
        } else {
            int gk = kb + bk_n;
#pragma unroll
            for (int s = 0; s < 4; s++) {
                int gn = n0 + bn_n + s;
                float2 v = make_float2(0.f, 0.f);
                if (gk < K && gn < N) v = ((const float2*)Bb)[(size_t)gk * ldb + gn];
                ((float2*)shB)[bk_n * LB + bn_n + s] = v;
            }
        }
        __syncthreads();
        // ---- compute ----
#pragma unroll
        for (int kk = 0; kk < BK; kk++) {
            float ar[2], ai[2];
#pragma unroll
            for (int mi = 0; mi < 2; mi++) {
                if (AREAL) {
                    ar[mi] = shA[kk * LA + ty * 2 + mi]; ai[mi] = 0.f;
                } else {
                    float2 a = ((const float2*)shA)[kk * LA + ty * 2 + mi];
                    ar[mi] = a.x; ai[mi] = a.y;
                }
            }
            float br[4], bi[4];
#pragma unroll
            for (int ni = 0; ni < 4; ni++) {
                if (BREALT) {
                    br[ni] = shB[kk * LB + tx * 4 + ni]; bi[ni] = 0.f;
                } else {
                    float2 bv = ((const float2*)shB)[kk * LB + tx * 4 + ni];
                    br[ni] = bv.x; bi[ni] = bv.y;
                }
            }
#pragma unroll
            for (int mi = 0; mi < 2; mi++)
#pragma unroll
                for (int ni = 0; ni < 4; ni++) {
                    if (AREAL) {
                        acc[mi][ni][0] += ar[mi] * br[ni];
                        acc[mi][ni][1] += ar[mi] * bi[ni];
                    } else if (BREALT) {
                        acc[mi][ni][0] += ar[mi] * br[ni];
                        acc[mi][ni][1] += ai[mi] * br[ni];
                    } else {
                        acc[mi][ni][0] += ar[mi] * br[ni] - ai[mi] * bi[ni];
                        acc[mi][ni][1] += ar[mi] * bi[ni] + ai[mi] * br[ni];
                    }
                }
        }
        __syncthreads();
    }
    // ---- epilogue ----
#pragma unroll
    for (int mi = 0; mi < 2; mi++) {
        int m = m0 + ty * 2 + mi;
        if (m >= M) continue;
#pragma unroll
        for (int ni = 0; ni < 4; ni++) {
            int n = n0 + tx * 4 + ni;
            if (n >= N) continue;
            size_t o = ((size_t)m * ldc + n) * 2;
            if (CADD) {
                Cb[o]     += scale * acc[mi][ni][0];
                Cb[o + 1] += scale * acc[mi][ni][1];
            } else {
                Cb[o]     = scale * acc[mi][ni][0];
                Cb[o + 1] = scale * acc[mi][ni][1];
            }
        }
    }
}

// --------------------------- complex 3x3 conv (per-batch weights) -----------
// Each thread computes ALL COUT channels for one pixel.
// forward: w[b][COUT][CIN][3][3]; adjoint: conj(w[b][CIN][COUT][3][3])^T(pq)
template<int CIN, int COUT, int ADJ>
__global__ __launch_bounds__(256) void k_convN(
        const float* __restrict__ in, float* __restrict__ out,
        const float* __restrict__ wre, const float* __restrict__ wim) {
    const int b = blockIdx.y;
    __shared__ float wsr[COUT * CIN * 9], wsi[COUT * CIN * 9];
    const int tid = threadIdx.x;
    if (tid < COUT * CIN * 9) {
        int o = tid / (CIN * 9), rem = tid % (CIN * 9);
        int ci = rem / 9, k = rem % 9, p = k / 3, q = k % 3;
        int widx; float sg;
        if (!ADJ) { widx = ((b * COUT + o) * CIN + ci) * 9 + p * 3 + q; sg = 1.f; }
        else      { widx = ((b * CIN + ci) * COUT + o) * 9 + q * 3 + p; sg = -1.f; }
        wsr[tid] = wre[widx];
        wsi[tid] = sg * wim[widx];
    }
    __syncthreads();
    const int pix = blockIdx.x * 256 + tid;
    if (pix >= MM) return;
    const int y = pix / 257, x = pix % 257;
    const bool interior = (y >= 1) & (y <= 255) & (x >= 1) & (x <= 255);
    float accr[COUT], acci[COUT];
#pragma unroll
    for (int o = 0; o < COUT; o++) { accr[o] = 0.f; acci[o] = 0.f; }
    const float2* ipb = (const float2*)in + (size_t)b * CIN * MM;
#pragma unroll
    for (int ci = 0; ci < CIN; ci++) {
        float vr[9], vi[9];
        const float2* c = ipb + (size_t)ci * MM;
        if (interior) {
            const float2* r0 = c + (size_t)(y - 1) * 257 + (x - 1);
#pragma unroll
            for (int p = 0; p < 3; p++)
#pragma unroll
                for (int q = 0; q < 3; q++) {
                    float2 v = r0[p * 257 + q];
                    vr[p * 3 + q] = v.x; vi[p * 3 + q] = v.y;
                }
        } else {
#pragma unroll
            for (int p = 0; p < 3; p++)
#pragma unroll
                for (int q = 0; q < 3; q++) {
                    int yy = y + p - 1, xx = x + q - 1;
                    float2 v = make_float2(0.f, 0.f);
                    if (yy >= 0 && yy < 257 && xx >= 0 && xx < 257)
                        v = c[(size_t)yy * 257 + xx];
                    vr[p * 3 + q] = v.x; vi[p * 3 + q] = v.y;
                }
        }
#pragma unroll
        for (int o = 0; o < COUT; o++) {
#pragma unroll
            for (int k = 0; k < 9; k++) {
                float wr = wsr[(o * CIN + ci) * 9 + k];
                float wi = wsi[(o * CIN + ci) * 9 + k];
                accr[o] += vr[k] * wr - vi[k] * wi;
                acci[o] += vr[k] * wi + vi[k] * wr;
            }
        }
    }
    float2* ob = (float2*)out + (size_t)b * COUT * MM + pix;
#pragma unroll
    for (int o = 0; o < COUT; o++)
        ob[(size_t)o * MM] = make_float2(accr[o], acci[o]);
}

// --------------------------- elementwise wt multiply ------------------------
__global__ void k_wtmul(const float* __restrict__ in, const float* __restrict__ wtr,
                        const float* __restrict__ wti, float* __restrict__ out) {
    int t = blockIdx.x * 256 + threadIdx.x;
    if (t >= BB * MM) return;
    float ar = in[2 * t], ai = in[2 * t + 1];
    float wr = wtr[t], wi = wti[t];
    out[2 * t] = ar * wr - ai * wi;
    out[2 * t + 1] = ar * wi + ai * wr;
}

// --------------------------- norm reduction ---------------------------------
__global__ void k_reduce(const float* __restrict__ r, const float* __restrict__ fr,
                         const float* __restrict__ fi, float* __restrict__ acc) {
    int b = blockIdx.y;
    int tid = threadIdx.x;
    float sr = 0.f, sf = 0.f;
    for (int idx = blockIdx.x * 256 + tid; idx < NN; idx += gridDim.x * 256) {
        const float* rp = r + ((size_t)b * NN + idx) * 2;
        float rx = rp[0], ry = rp[1];
        sr += rx * rx + ry * ry;
        float a = fr[(size_t)b * NN + idx], c = fi[(size_t)b * NN + idx];
        sf += a * a + c * c;
    }
    for (int off = 32; off > 0; off >>= 1) {
        sr += __shfl_down(sr, off);
        sf += __shfl_down(sf, off);
    }
    __shared__ float ssr[4], ssf[4];
    int wid = tid >> 6, lane = tid & 63;
    if (lane == 0) { ssr[wid] = sr; ssf[wid] = sf; }
    __syncthreads();
    if (tid == 0) {
        float tr = ssr[0] + ssr[1] + ssr[2] + ssr[3];
        float tf = ssf[0] + ssf[1] + ssf[2] + ssf[3];
        atomicAdd(&acc[2 * b], tr);
        atomicAdd(&acc[2 * b + 1], tf);
    }
}

__global__ void k_finalize(const float* __restrict__ acc, float* __restrict__ out) {
    if (threadIdx.x == 0 && blockIdx.x == 0) {
        float num = 0.f, den = 0.f;
        for (int b = 0; b < BB; b++) {
            num += sqrtf(acc[2 * b]);
            den += sqrtf(acc[2 * b + 1]);
        }
        out[0] = num / den;
    }
}

// ---------------------------------------------------------------------------
extern "C" void kernel_launch(void* const* d_in, const int* in_sizes, int n_in,
                              void* d_out, int out_size, void* d_ws, size_t ws_size,
                              hipStream_t stream) {
    (void)in_sizes; (void)n_in; (void)out_size; (void)ws_size;
    const float* fr  = (const float*)d_in[0];
    const float* fi  = (const float*)d_in[1];
    const float* kap = (const float*)d_in[2];
    const float* w1r = (const float*)d_in[3];
    const float* w1i = (const float*)d_in[4];
    const float* w2r = (const float*)d_in[5];
    const float* w2i = (const float*)d_in[6];
    const float* w3r = (const float*)d_in[7];
    const float* w3i = (const float*)d_in[8];
    const float* wtr = (const float*)d_in[9];
    const float* wti = (const float*)d_in[10];
    const int K = 3;   // epoch=81 -> (81-1)/40+1

    float* ws = (float*)d_ws;
    size_t off = 0;
    float* x0   = ws + off; off += (size_t)BB * NN * 2;
    float* x1   = ws + off; off += (size_t)BB * NN * 2;
    float* rb   = ws + off; off += (size_t)BB * NN * 2;
    float* kap2 = ws + off; off += (size_t)BB * NN;
    float* dinv = ws + off; off += (size_t)BB * NN;
    float* tA   = ws + off; off += (size_t)BB * MM * 2;
    float* tB   = ws + off; off += (size_t)BB * MM * 2;
    float* c4a  = ws + off; off += (size_t)BB * 4 * MM * 2;
    float* c4b  = ws + off; off += (size_t)BB * 4 * MM * 2;
    float* S    = ws + off; off += 257 * 256;
    float* W    = ws + off; off += 256 * 257 * 2;
    float* WT   = ws + off; off += 257 * 256 * 2;
    float* acc  = ws + off; off += 16;

    const long MB = (long)MM * 2;   // per-batch cplx matrix stride (floats)

    int sgrid = (BB * NN + 255) / 256;
    k_init<<<sgrid, 256, 0, stream>>>(kap, kap2, dinv, x0, acc);
    k_mats<<<(MSZ * MSZ + 255) / 256, 256, 0, stream>>>(S, W, WT);

    float* xc = x0;
    float* xo = x1;
    for (int it = 0; it < K; ++it) {
        for (int s = 0; s < 3; ++s) {
            k_step<<<sgrid, 256, 0, stream>>>(xc, xo, fr, fi, kap2, dinv, 0);
            float* t = xc; xc = xo; xo = t;
        }
        k_step<<<sgrid, 256, 0, stream>>>(xc, rb, fr, fi, kap2, dinv, 1);
        // DST pass 1: tA[u][p] = sum_m S[u][m] * rb[m][p]        (257x256x256)
        cgemm<1, 0, 0><<<dim3(4, 9, BB), 256, 0, stream>>>(
            S, rb, tA, 257, 256, 256, 256, 256, 256, 0, (long)NN * 2, MB, 1.f);
        // DST pass 2: tB[u][v] = C1 * sum_p tA[u][p] * S[v][p]   (257x257x256)
        cgemm<0, 1, 0><<<dim3(5, 9, BB), 256, 0, stream>>>(
            tA, S, tB, 257, 257, 256, 256, 256, 257, MB, 0, MB, C1F);
        // conv chain forward
        k_convN<1, 4, 0><<<dim3(259, BB), 256, 0, stream>>>(tB, c4a, w1r, w1i);
        k_convN<4, 4, 0><<<dim3(259, BB), 256, 0, stream>>>(c4a, c4b, w2r, w2i);
        k_convN<4, 1, 0><<<dim3(259, BB), 256, 0, stream>>>(c4b, tA, w3r, w3i);
        k_wtmul<<<(BB * MM + 255) / 256, 256, 0, stream>>>(tA, wtr, wti, tB);
        // conv chain adjoint
        k_convN<1, 4, 1><<<dim3(259, BB), 256, 0, stream>>>(tB, c4a, w3r, w3i);
        k_convN<4, 4, 1><<<dim3(259, BB), 256, 0, stream>>>(c4a, c4b, w2r, w2i);
        k_convN<4, 1, 1><<<dim3(259, BB), 256, 0, stream>>>(c4b, tA, w1r, w1i);
        // DFT pass 1: tB[k][v] = sum_u W[k][u] * tA[u][v]        (256x257x257)
        cgemm<0, 0, 0><<<dim3(5, 8, BB), 256, 0, stream>>>(
            W, tA, tB, 256, 257, 257, 257, 257, 257, 0, MB, MB, 1.f);
        // DFT pass 2 + add: xc[k][l] += sum_v tB[k][v] * WT[v][l] (256x256x257)
        cgemm<0, 0, 1><<<dim3(4, 8, BB), 256, 0, stream>>>(
            tB, WT, xc, 256, 256, 257, 257, 256, 256, MB, 0, (long)NN * 2, 1.f);
    }
    k_step<<<sgrid, 256, 0, stream>>>(xc, rb, fr, fi, kap2, dinv, 1);
    k_reduce<<<dim3(32, BB), 256, 0, stream>>>(rb, fr, fi, acc);
    k_finalize<<<1, 64, 0, stream>>>(acc, (float*)d_out);
}

// Round 3
// 1198.372 us; speedup vs baseline: 1.2560x; 1.2010x over previous
//
#include <hip/hip_runtime.h>

// ---------------------------------------------------------------------------
// HyperFNS: Helmholtz Jacobi + FNS spectral correction, B=8, N=256, K=3.
// FFTs collapsed analytically into sine/DFT matrix products, executed as
// LDS-tiled complex GEMMs. Conv: one output channel per thread (occupancy).
// ---------------------------------------------------------------------------

#define BB 8
#define NSZ 256
#define NN 65536          // 256*256
#define MSZ 257
#define MM 66049          // 257*257

constexpr double PI_D    = 3.14159265358979323846;
constexpr double OMEGA_D = 40.0 * PI_D;           // N=256 -> omega = 40*pi
constexpr double H_D     = 1.0 / 255.0;
constexpr float  OMEGA2F = (float)(OMEGA_D * OMEGA_D);
constexpr float  BCVF    = (float)(2.0 * H_D * OMEGA_D);   // bc = i*BCVF
constexpr float  INVH2F  = 65025.0f;                        // 1/h^2 = 255^2
constexpr float  C1F     = (float)(-4.0 / (514.0 * 514.0)); // ifft2 odd-sym factor
constexpr float  TP514   = (float)(2.0 * PI_D / 514.0);

// --------------------------- init: kappa2, dinv, x=0, acc=0 -----------------
__global__ void k_init(const float* __restrict__ kappa, float* __restrict__ kap2,
                       float* __restrict__ dinv, float* __restrict__ x0,
                       float* __restrict__ acc) {
    int t = blockIdx.x * 256 + threadIdx.x;
    if (t < BB * NN) {
        float k = kappa[t];
        float k2 = k * k;
        kap2[t] = k2;
        dinv[t] = 1.0f / (4.0f * INVH2F - OMEGA2F * k2);
        x0[2 * t] = 0.f; x0[2 * t + 1] = 0.f;
    }
    if (t < 16) acc[t] = 0.f;
}

// --------------------------- transform matrices -----------------------------
// S [u<257][m<256]  = sin(2*pi*(u-128)*(m+1)/514)
// W [k<256][u<257]  = (-1)^k * exp(-2*pi*i*k*(u+129)/514)
// WT[v<257][l<256]  = W[l][v]
__global__ void k_mats(float* __restrict__ S, float* __restrict__ W,
                       float* __restrict__ WT) {
    int t = blockIdx.x * 256 + threadIdx.x;
    if (t >= MSZ * MSZ) return;
    int i = t / 257, j = t % 257;
    if (j < 256) {
        int a = (i - 128) * (j + 1);
        int m = ((a % 514) + 514) % 514;
        S[i * 256 + j] = sinf(m * TP514);
    }
    if (i < 256) {
        int tt = (i * (j + 129)) % 514;
        float cc = cosf(tt * TP514), ss = sinf(tt * TP514);
        float sg = (i & 1) ? -1.f : 1.f;
        W[(i * 257 + j) * 2] = sg * cc;
        W[(i * 257 + j) * 2 + 1] = -sg * ss;
    }
    if (j < 256) {
        int tt = (j * (i + 129)) % 514;
        float cc = cosf(tt * TP514), ss = sinf(tt * TP514);
        float sg = (j & 1) ? -1.f : 1.f;
        WT[(i * 256 + j) * 2] = sg * cc;
        WT[(i * 256 + j) * 2 + 1] = -sg * ss;
    }
}

// --------------------------- stencil: smooth / residual ---------------------
__global__ void k_step(const float* __restrict__ xin, float* __restrict__ out,
                       const float* __restrict__ fr, const float* __restrict__ fi,
                       const float* __restrict__ kap2, const float* __restrict__ dinv,
                       int mode) {
    int t = blockIdx.x * 256 + threadIdx.x;
    if (t >= BB * NN) return;
    int b = t >> 16;
    int ij = t & 65535;
    int i = ij >> 8, j = ij & 255;
    const float* xb = xin + (size_t)b * NN * 2;
    float xcr = xb[2 * ij], xci = xb[2 * ij + 1];
    float ur, ui, dr, di, lr, li, rr, ri;
    if (i > 0) { int n = ij - 256; ur = xb[2 * n]; ui = xb[2 * n + 1]; }
    else { int n = 256 + j; ur = xb[2 * n] - BCVF * xci; ui = xb[2 * n + 1] + BCVF * xcr; }
    if (i < 255) { int n = ij + 256; dr = xb[2 * n]; di = xb[2 * n + 1]; }
    else { int n = 254 * 256 + j; dr = xb[2 * n] - BCVF * xci; di = xb[2 * n + 1] + BCVF * xcr; }
    if (j > 0) { int n = ij - 1; lr = xb[2 * n]; li = xb[2 * n + 1]; }
    else { int n = i * 256 + 1; lr = xb[2 * n] - BCVF * xci; li = xb[2 * n + 1] + BCVF * xcr; }
    if (j < 255) { int n = ij + 1; rr = xb[2 * n]; ri = xb[2 * n + 1]; }
    else { int n = i * 256 + 254; rr = xb[2 * n] - BCVF * xci; ri = xb[2 * n + 1] + BCVF * xcr; }
    float k2 = kap2[t];
    float axr = (4.f * xcr - ur - dr - lr - rr) * INVH2F - OMEGA2F * k2 * xcr;
    float axi = (4.f * xci - ui - di - li - ri) * INVH2F - OMEGA2F * k2 * xci;
    float resr = fr[t] - axr, resi = fi[t] - axi;
    if (mode == 0) {
        float dv = dinv[t] * (2.0f / 3.0f);
        out[2 * t] = xcr + dv * resr;
        out[2 * t + 1] = xci + dv * resi;
    } else {
        out[2 * t] = resr;
        out[2 * t + 1] = resi;
    }
}

// --------------------------- tiled complex GEMM -----------------------------
// C[m][n] (+)= scale * sum_k A[m][k] * B[k][n]
// AREAL : A is real float matrix (lda in floats)
// BREALT: B is real and transposed: B[k][n] = Bg[n*ldb + k]
// CADD  : accumulate into C instead of overwrite
// Tiles: BM=32 x BN=64 x BK=16, 256 threads, per-thread 2x4 complex acc.
template<int AREAL, int BREALT, int CADD>
__global__ __launch_bounds__(256) void cgemm(
        const float* __restrict__ A, const float* __restrict__ Bg,
        float* __restrict__ C, int M, int N, int K,
        int lda, int ldb, int ldc,
        long aBatch, long bBatch, long cBatch, float scale) {
    constexpr int BM = 32, BN = 64, BK = 16;
    constexpr int LA = AREAL ? (BM + 1) : (BM + 2);   // row stride (elems)
    constexpr int LB = BREALT ? (BN + 1) : (BN + 2);
    __shared__ float shA[AREAL ? BK * LA : BK * LA * 2];
    __shared__ float shB[BREALT ? BK * LB : BK * LB * 2];

    const int tid = threadIdx.x;
    const int bz = blockIdx.z;
    const float* Ab = A + (size_t)bz * aBatch;
    const float* Bb = Bg + (size_t)bz * bBatch;
    float* Cb = C + (size_t)bz * cBatch;

    const int m0 = blockIdx.y * BM;
    const int n0 = blockIdx.x * BN;

    const int am = tid >> 3;
    const int ak = (tid & 7) * 2;
    const int bk_n = tid >> 4;
    const int bn_n = (tid & 15) * 4;
    const int bn_t = tid >> 2;
    const int bk_t = (tid & 3) * 4;

    const int ty = tid >> 4;
    const int tx = tid & 15;

    float acc[2][4][2];
#pragma unroll
    for (int i = 0; i < 2; i++)
#pragma unroll
        for (int j = 0; j < 4; j++) { acc[i][j][0] = 0.f; acc[i][j][1] = 0.f; }

    const int nkt = (K + BK - 1) / BK;
    for (int kt = 0; kt < nkt; kt++) {
        const int kb = kt * BK;
        {
            int gm = m0 + am;
#pragma unroll
            for (int s = 0; s < 2; s++) {
                int gk = kb + ak + s;
                if (AREAL) {
                    float v = (gm < M && gk < K) ? Ab[(size_t)gm * lda + gk] : 0.f;
                    shA[(ak + s) * LA + am] = v;
                } else {
                    float2 v = make_float2(0.f, 0.f);
                    if (gm < M && gk < K) v = ((const float2*)Ab)[(size_t)gm * lda + gk];
                    ((float2*)shA)[(ak + s) * LA + am] = v;
                }
            }
        }
        if (BREALT) {
            int gn = n0 + bn_t;
#pragma unroll
            for (int s = 0; s < 4; s++) {
                int gk = kb + bk_t + s;
                float v = (gk < K && gn < N) ? Bb[(size_t)gn * ldb + gk] : 0.f;
                shB[(bk_t + s) * LB + bn_t] = v;
            }
        } else {
            int gk = kb + bk_n;
#pragma unroll
            for (int s = 0; s < 4; s++) {
                int gn = n0 + bn_n + s;
                float2 v = make_float2(0.f, 0.f);
                if (gk < K && gn < N) v = ((const float2*)Bb)[(size_t)gk * ldb + gn];
                ((float2*)shB)[bk_n * LB + bn_n + s] = v;
            }
        }
        __syncthreads();
#pragma unroll
        for (int kk = 0; kk < BK; kk++) {
            float ar[2], ai[2];
#pragma unroll
            for (int mi = 0; mi < 2; mi++) {
                if (AREAL) {
                    ar[mi] = shA[kk * LA + ty * 2 + mi]; ai[mi] = 0.f;
                } else {
                    float2 a = ((const float2*)shA)[kk * LA + ty * 2 + mi];
                    ar[mi] = a.x; ai[mi] = a.y;
                }
            }
            float br[4], bi[4];
#pragma unroll
            for (int ni = 0; ni < 4; ni++) {
                if (BREALT) {
                    br[ni] = shB[kk * LB + tx * 4 + ni]; bi[ni] = 0.f;
                } else {
                    float2 bv = ((const float2*)shB)[kk * LB + tx * 4 + ni];
                    br[ni] = bv.x; bi[ni] = bv.y;
                }
            }
#pragma unroll
            for (int mi = 0; mi < 2; mi++)
#pragma unroll
                for (int ni = 0; ni < 4; ni++) {
                    if (AREAL) {
                        acc[mi][ni][0] += ar[mi] * br[ni];
                        acc[mi][ni][1] += ar[mi] * bi[ni];
                    } else if (BREALT) {
                        acc[mi][ni][0] += ar[mi] * br[ni];
                        acc[mi][ni][1] += ai[mi] * br[ni];
                    } else {
                        acc[mi][ni][0] += ar[mi] * br[ni] - ai[mi] * bi[ni];
                        acc[mi][ni][1] += ar[mi] * bi[ni] + ai[mi] * br[ni];
                    }
                }
        }
        __syncthreads();
    }
#pragma unroll
    for (int mi = 0; mi < 2; mi++) {
        int m = m0 + ty * 2 + mi;
        if (m >= M) continue;
#pragma unroll
        for (int ni = 0; ni < 4; ni++) {
            int n = n0 + tx * 4 + ni;
            if (n >= N) continue;
            size_t o = ((size_t)m * ldc + n) * 2;
            if (CADD) {
                Cb[o]     += scale * acc[mi][ni][0];
                Cb[o + 1] += scale * acc[mi][ni][1];
            } else {
                Cb[o]     = scale * acc[mi][ni][0];
                Cb[o + 1] = scale * acc[mi][ni][1];
            }
        }
    }
}

// --------------------------- complex 3x3 conv -------------------------------
// One output channel per thread: block = (pixel tile), grid.y = out channel,
// grid.z = batch. Low VGPR -> 8 waves/SIMD; 259*COUT*BB blocks for MLP.
// forward: w[b][COUT][CIN][3][3]; adjoint: conj(w[b][CIN][COUT][3][3])^T(pq)
template<int CIN, int ADJ>
__global__ __launch_bounds__(256) void k_conv1(
        const float* __restrict__ in, float* __restrict__ out,
        const float* __restrict__ wre, const float* __restrict__ wim, int COUT) {
    const int b = blockIdx.z, o = blockIdx.y;
    __shared__ float wsr[CIN * 9], wsi[CIN * 9];
    const int tid = threadIdx.x;
    if (tid < CIN * 9) {
        int ci = tid / 9, k = tid % 9, p = k / 3, q = k % 3;
        int widx; float sg;
        if (!ADJ) { widx = ((b * COUT + o) * CIN + ci) * 9 + p * 3 + q; sg = 1.f; }
        else      { widx = ((b * CIN + ci) * COUT + o) * 9 + q * 3 + p; sg = -1.f; }
        wsr[tid] = wre[widx];
        wsi[tid] = sg * wim[widx];
    }
    __syncthreads();
    const int pix = blockIdx.x * 256 + tid;
    if (pix >= MM) return;
    const int y = pix / 257, x = pix % 257;
    const bool interior = (y >= 1) & (y <= 255) & (x >= 1) & (x <= 255);
    float ar = 0.f, ai = 0.f;
    const float2* ipb = (const float2*)in + (size_t)b * CIN * MM;
#pragma unroll
    for (int ci = 0; ci < CIN; ci++) {
        const float2* c = ipb + (size_t)ci * MM;
        if (interior) {
            const float2* r0 = c + (size_t)(y - 1) * 257 + (x - 1);
#pragma unroll
            for (int p = 0; p < 3; p++)
#pragma unroll
                for (int q = 0; q < 3; q++) {
                    float2 v = r0[p * 257 + q];
                    float wr = wsr[ci * 9 + p * 3 + q];
                    float wi = wsi[ci * 9 + p * 3 + q];
                    ar += v.x * wr - v.y * wi;
                    ai += v.x * wi + v.y * wr;
                }
        } else {
#pragma unroll
            for (int p = 0; p < 3; p++)
#pragma unroll
                for (int q = 0; q < 3; q++) {
                    int yy = y + p - 1, xx = x + q - 1;
                    if (yy < 0 || yy >= 257 || xx < 0 || xx >= 257) continue;
                    float2 v = c[(size_t)yy * 257 + xx];
                    float wr = wsr[ci * 9 + p * 3 + q];
                    float wi = wsi[ci * 9 + p * 3 + q];
                    ar += v.x * wr - v.y * wi;
                    ai += v.x * wi + v.y * wr;
                }
        }
    }
    float2* ob = (float2*)out + ((size_t)b * COUT + o) * MM + pix;
    *ob = make_float2(ar, ai);
}

// --------------------------- elementwise wt multiply ------------------------
__global__ void k_wtmul(const float* __restrict__ in, const float* __restrict__ wtr,
                        const float* __restrict__ wti, float* __restrict__ out) {
    int t = blockIdx.x * 256 + threadIdx.x;
    if (t >= BB * MM) return;
    float ar = in[2 * t], ai = in[2 * t + 1];
    float wr = wtr[t], wi = wti[t];
    out[2 * t] = ar * wr - ai * wi;
    out[2 * t + 1] = ar * wi + ai * wr;
}

// --------------------------- norm reduction ---------------------------------
__global__ void k_reduce(const float* __restrict__ r, const float* __restrict__ fr,
                         const float* __restrict__ fi, float* __restrict__ acc) {
    int b = blockIdx.y;
    int tid = threadIdx.x;
    float sr = 0.f, sf = 0.f;
    for (int idx = blockIdx.x * 256 + tid; idx < NN; idx += gridDim.x * 256) {
        const float* rp = r + ((size_t)b * NN + idx) * 2;
        float rx = rp[0], ry = rp[1];
        sr += rx * rx + ry * ry;
        float a = fr[(size_t)b * NN + idx], c = fi[(size_t)b * NN + idx];
        sf += a * a + c * c;
    }
    for (int off = 32; off > 0; off >>= 1) {
        sr += __shfl_down(sr, off);
        sf += __shfl_down(sf, off);
    }
    __shared__ float ssr[4], ssf[4];
    int wid = tid >> 6, lane = tid & 63;
    if (lane == 0) { ssr[wid] = sr; ssf[wid] = sf; }
    __syncthreads();
    if (tid == 0) {
        float tr = ssr[0] + ssr[1] + ssr[2] + ssr[3];
        float tf = ssf[0] + ssf[1] + ssf[2] + ssf[3];
        atomicAdd(&acc[2 * b], tr);
        atomicAdd(&acc[2 * b + 1], tf);
    }
}

__global__ void k_finalize(const float* __restrict__ acc, float* __restrict__ out) {
    if (threadIdx.x == 0 && blockIdx.x == 0) {
        float num = 0.f, den = 0.f;
        for (int b = 0; b < BB; b++) {
            num += sqrtf(acc[2 * b]);
            den += sqrtf(acc[2 * b + 1]);
        }
        out[0] = num / den;
    }
}

// ---------------------------------------------------------------------------
extern "C" void kernel_launch(void* const* d_in, const int* in_sizes, int n_in,
                              void* d_out, int out_size, void* d_ws, size_t ws_size,
                              hipStream_t stream) {
    (void)in_sizes; (void)n_in; (void)out_size; (void)ws_size;
    const float* fr  = (const float*)d_in[0];
    const float* fi  = (const float*)d_in[1];
    const float* kap = (const float*)d_in[2];
    const float* w1r = (const float*)d_in[3];
    const float* w1i = (const float*)d_in[4];
    const float* w2r = (const float*)d_in[5];
    const float* w2i = (const float*)d_in[6];
    const float* w3r = (const float*)d_in[7];
    const float* w3i = (const float*)d_in[8];
    const float* wtr = (const float*)d_in[9];
    const float* wti = (const float*)d_in[10];
    const int K = 3;   // epoch=81 -> (81-1)/40+1

    float* ws = (float*)d_ws;
    size_t off = 0;
    float* x0   = ws + off; off += (size_t)BB * NN * 2;
    float* x1   = ws + off; off += (size_t)BB * NN * 2;
    float* rb   = ws + off; off += (size_t)BB * NN * 2;
    float* kap2 = ws + off; off += (size_t)BB * NN;
    float* dinv = ws + off; off += (size_t)BB * NN;
    float* tA   = ws + off; off += (size_t)BB * MM * 2;
    float* tB   = ws + off; off += (size_t)BB * MM * 2;
    float* c4a  = ws + off; off += (size_t)BB * 4 * MM * 2;
    float* c4b  = ws + off; off += (size_t)BB * 4 * MM * 2;
    float* S    = ws + off; off += 257 * 256;
    float* W    = ws + off; off += 256 * 257 * 2;
    float* WT   = ws + off; off += 257 * 256 * 2;
    float* acc  = ws + off; off += 16;

    const long MB = (long)MM * 2;   // per-batch cplx matrix stride (floats)

    int sgrid = (BB * NN + 255) / 256;
    k_init<<<sgrid, 256, 0, stream>>>(kap, kap2, dinv, x0, acc);
    k_mats<<<(MSZ * MSZ + 255) / 256, 256, 0, stream>>>(S, W, WT);

    float* xc = x0;
    float* xo = x1;
    for (int it = 0; it < K; ++it) {
        for (int s = 0; s < 3; ++s) {
            k_step<<<sgrid, 256, 0, stream>>>(xc, xo, fr, fi, kap2, dinv, 0);
            float* t = xc; xc = xo; xo = t;
        }
        k_step<<<sgrid, 256, 0, stream>>>(xc, rb, fr, fi, kap2, dinv, 1);
        // DST pass 1: tA[u][p] = sum_m S[u][m] * rb[m][p]        (257x256x256)
        cgemm<1, 0, 0><<<dim3(4, 9, BB), 256, 0, stream>>>(
            S, rb, tA, 257, 256, 256, 256, 256, 256, 0, (long)NN * 2, MB, 1.f);
        // DST pass 2: tB[u][v] = C1 * sum_p tA[u][p] * S[v][p]   (257x257x256)
        cgemm<0, 1, 0><<<dim3(5, 9, BB), 256, 0, stream>>>(
            tA, S, tB, 257, 257, 256, 256, 256, 257, MB, 0, MB, C1F);
        // conv chain forward
        k_conv1<1, 0><<<dim3(259, 4, BB), 256, 0, stream>>>(tB, c4a, w1r, w1i, 4);
        k_conv1<4, 0><<<dim3(259, 4, BB), 256, 0, stream>>>(c4a, c4b, w2r, w2i, 4);
        k_conv1<4, 0><<<dim3(259, 1, BB), 256, 0, stream>>>(c4b, tA, w3r, w3i, 1);
        k_wtmul<<<(BB * MM + 255) / 256, 256, 0, stream>>>(tA, wtr, wti, tB);
        // conv chain adjoint
        k_conv1<1, 1><<<dim3(259, 4, BB), 256, 0, stream>>>(tB, c4a, w3r, w3i, 4);
        k_conv1<4, 1><<<dim3(259, 4, BB), 256, 0, stream>>>(c4a, c4b, w2r, w2i, 4);
        k_conv1<4, 1><<<dim3(259, 1, BB), 256, 0, stream>>>(c4b, tA, w1r, w1i, 1);
        // DFT pass 1: tB[k][v] = sum_u W[k][u] * tA[u][v]        (256x257x257)
        cgemm<0, 0, 0><<<dim3(5, 8, BB), 256, 0, stream>>>(
            W, tA, tB, 256, 257, 257, 257, 257, 257, 0, MB, MB, 1.f);
        // DFT pass 2 + add: xc[k][l] += sum_v tB[k][v] * WT[v][l] (256x256x257)
        cgemm<0, 0, 1><<<dim3(4, 8, BB), 256, 0, stream>>>(
            tB, WT, xc, 256, 256, 257, 257, 256, 256, MB, 0, (long)NN * 2, 1.f);
    }
    k_step<<<sgrid, 256, 0, stream>>>(xc, rb, fr, fi, kap2, dinv, 1);
    k_reduce<<<dim3(32, BB), 256, 0, stream>>>(rb, fr, fi, acc);
    k_finalize<<<1, 64, 0, stream>>>(acc, (float*)d_out);
}

// Round 4
// 1075.656 us; speedup vs baseline: 1.3993x; 1.1141x over previous
//
#include <hip/hip_runtime.h>

// ---------------------------------------------------------------------------
// HyperFNS: Helmholtz Jacobi + FNS spectral correction, B=8, N=256, K=3.
// FFTs collapsed analytically into sine/DFT matrix products, executed as
// LDS-tiled complex GEMMs (32x32 tiles, strided conflict-free mapping).
// ---------------------------------------------------------------------------

#define BB 8
#define NSZ 256
#define NN 65536          // 256*256
#define MSZ 257
#define MM 66049          // 257*257

constexpr double PI_D    = 3.14159265358979323846;
constexpr double OMEGA_D = 40.0 * PI_D;           // N=256 -> omega = 40*pi
constexpr double H_D     = 1.0 / 255.0;
constexpr float  OMEGA2F = (float)(OMEGA_D * OMEGA_D);
constexpr float  BCVF    = (float)(2.0 * H_D * OMEGA_D);   // bc = i*BCVF
constexpr float  INVH2F  = 65025.0f;                        // 1/h^2 = 255^2
constexpr float  C1F     = (float)(-4.0 / (514.0 * 514.0)); // ifft2 odd-sym factor
constexpr float  TP514   = (float)(2.0 * PI_D / 514.0);

// --------------------------- init: kappa2, dinv, x=0, acc=0 -----------------
__global__ void k_init(const float* __restrict__ kappa, float* __restrict__ kap2,
                       float* __restrict__ dinv, float* __restrict__ x0,
                       float* __restrict__ acc) {
    int t = blockIdx.x * 256 + threadIdx.x;
    if (t < BB * NN) {
        float k = kappa[t];
        float k2 = k * k;
        kap2[t] = k2;
        dinv[t] = 1.0f / (4.0f * INVH2F - OMEGA2F * k2);
        x0[2 * t] = 0.f; x0[2 * t + 1] = 0.f;
    }
    if (t < 16) acc[t] = 0.f;
}

// --------------------------- transform matrices -----------------------------
// S [u<257][m<256]  = sin(2*pi*(u-128)*(m+1)/514)
// W [k<256][u<257]  = (-1)^k * exp(-2*pi*i*k*(u+129)/514)
// WT[v<257][l<256]  = W[l][v]
__global__ void k_mats(float* __restrict__ S, float* __restrict__ W,
                       float* __restrict__ WT) {
    int t = blockIdx.x * 256 + threadIdx.x;
    if (t >= MSZ * MSZ) return;
    int i = t / 257, j = t % 257;
    if (j < 256) {
        int a = (i - 128) * (j + 1);
        int m = ((a % 514) + 514) % 514;
        S[i * 256 + j] = sinf(m * TP514);
    }
    if (i < 256) {
        int tt = (i * (j + 129)) % 514;
        float cc = cosf(tt * TP514), ss = sinf(tt * TP514);
        float sg = (i & 1) ? -1.f : 1.f;
        W[(i * 257 + j) * 2] = sg * cc;
        W[(i * 257 + j) * 2 + 1] = -sg * ss;
    }
    if (j < 256) {
        int tt = (j * (i + 129)) % 514;
        float cc = cosf(tt * TP514), ss = sinf(tt * TP514);
        float sg = (j & 1) ? -1.f : 1.f;
        WT[(i * 256 + j) * 2] = sg * cc;
        WT[(i * 256 + j) * 2 + 1] = -sg * ss;
    }
}

// --------------------------- stencil: smooth / residual ---------------------
__global__ void k_step(const float* __restrict__ xin, float* __restrict__ out,
                       const float* __restrict__ fr, const float* __restrict__ fi,
                       const float* __restrict__ kap2, const float* __restrict__ dinv,
                       int mode) {
    int t = blockIdx.x * 256 + threadIdx.x;
    if (t >= BB * NN) return;
    int b = t >> 16;
    int ij = t & 65535;
    int i = ij >> 8, j = ij & 255;
    const float* xb = xin + (size_t)b * NN * 2;
    float xcr = xb[2 * ij], xci = xb[2 * ij + 1];
    float ur, ui, dr, di, lr, li, rr, ri;
    if (i > 0) { int n = ij - 256; ur = xb[2 * n]; ui = xb[2 * n + 1]; }
    else { int n = 256 + j; ur = xb[2 * n] - BCVF * xci; ui = xb[2 * n + 1] + BCVF * xcr; }
    if (i < 255) { int n = ij + 256; dr = xb[2 * n]; di = xb[2 * n + 1]; }
    else { int n = 254 * 256 + j; dr = xb[2 * n] - BCVF * xci; di = xb[2 * n + 1] + BCVF * xcr; }
    if (j > 0) { int n = ij - 1; lr = xb[2 * n]; li = xb[2 * n + 1]; }
    else { int n = i * 256 + 1; lr = xb[2 * n] - BCVF * xci; li = xb[2 * n + 1] + BCVF * xcr; }
    if (j < 255) { int n = ij + 1; rr = xb[2 * n]; ri = xb[2 * n + 1]; }
    else { int n = i * 256 + 254; rr = xb[2 * n] - BCVF * xci; ri = xb[2 * n + 1] + BCVF * xcr; }
    float k2 = kap2[t];
    float axr = (4.f * xcr - ur - dr - lr - rr) * INVH2F - OMEGA2F * k2 * xcr;
    float axi = (4.f * xci - ui - di - li - ri) * INVH2F - OMEGA2F * k2 * xci;
    float resr = fr[t] - axr, resi = fi[t] - axi;
    if (mode == 0) {
        float dv = dinv[t] * (2.0f / 3.0f);
        out[2 * t] = xcr + dv * resr;
        out[2 * t + 1] = xci + dv * resi;
    } else {
        out[2 * t] = resr;
        out[2 * t + 1] = resi;
    }
}

// --------------------------- tiled complex GEMM -----------------------------
// C[m][n] (+)= scale * sum_k A[m][k] * B[k][n]
// AREAL : A real (lda = float stride); else cplx (lda = float2 stride)
// BREALT: B real transposed: B[k][n] = Bg[n*ldb + k]; else cplx row-major
// CADD  : accumulate into C
// BM=BN=32, BK=16, 256 threads, per-thread 2x2 cplx at (ty,ty+16)x(2tx,2tx+1).
template<int AREAL, int BREALT, int CADD>
__global__ __launch_bounds__(256) void cgemm(
        const float* __restrict__ A, const float* __restrict__ Bg,
        float* __restrict__ C, int M, int N, int K,
        int lda, int ldb, int ldc,
        long aBatch, long bBatch, long cBatch, float scale) {
    constexpr int BM = 32, BN = 32, BK = 16;
    constexpr int LA = 34;   // row stride: float2s (cplx) or floats (real), even
    constexpr int LB = 34;
    __shared__ float shA[AREAL ? BK * LA : BK * LA * 2];
    __shared__ float shB[BREALT ? BK * LB : BK * LB * 2];

    const int tid = threadIdx.x;
    const int bz = blockIdx.z;
    const float* Ab = A + (size_t)bz * aBatch;
    const float* Bb = Bg + (size_t)bz * bBatch;
    float* Cb = C + (size_t)bz * cBatch;

    const int m0 = blockIdx.y * BM;
    const int n0 = blockIdx.x * BN;

    const int ty = tid >> 4;       // 0..15 -> m = ty, ty+16
    const int tx = tid & 15;       // 0..15 -> n = 2tx, 2tx+1

    float acc[2][2][2];
#pragma unroll
    for (int i = 0; i < 2; i++)
#pragma unroll
        for (int j = 0; j < 2; j++) { acc[i][j][0] = 0.f; acc[i][j][1] = 0.f; }

    const int nkt = (K + BK - 1) / BK;
    for (int kt = 0; kt < nkt; kt++) {
        const int kb = kt * BK;
        // ---- load A tile: 32 m x 16 k ----
        {
            int am = tid >> 3;             // 0..31
            int ak = (tid & 7) * 2;        // 0..14
            int gm = m0 + am;
#pragma unroll
            for (int s = 0; s < 2; s++) {
                int gk = kb + ak + s;
                if (AREAL) {
                    float v = (gm < M && gk < K) ? Ab[(size_t)gm * lda + gk] : 0.f;
                    shA[(ak + s) * LA + am] = v;
                } else {
                    float2 v = make_float2(0.f, 0.f);
                    if (gm < M && gk < K) v = ((const float2*)Ab)[(size_t)gm * lda + gk];
                    ((float2*)shA)[(ak + s) * LA + am] = v;
                }
            }
        }
        // ---- load B tile: 16 k x 32 n ----
        if (BREALT) {
            int bn = tid >> 3;             // 0..31 (n)
            int bk = (tid & 7) * 2;        // 0..14 (k)
            int gn = n0 + bn;
#pragma unroll
            for (int s = 0; s < 2; s++) {
                int gk = kb + bk + s;
                float v = (gk < K && gn < N) ? Bb[(size_t)gn * ldb + gk] : 0.f;
                shB[(bk + s) * LB + bn] = v;
            }
        } else {
            int bk = tid >> 4;             // 0..15 (k)
            int bn = (tid & 15) * 2;       // 0..30 (n)
            int gk = kb + bk;
#pragma unroll
            for (int s = 0; s < 2; s++) {
                int gn = n0 + bn + s;
                float2 v = make_float2(0.f, 0.f);
                if (gk < K && gn < N) v = ((const float2*)Bb)[(size_t)gk * ldb + gn];
                ((float2*)shB)[bk * LB + bn + s] = v;
            }
        }
        __syncthreads();
        // ---- compute ----
#pragma unroll
        for (int kk = 0; kk < BK; kk++) {
            float ar[2], ai[2];
            if (AREAL) {
                ar[0] = shA[kk * LA + ty];      ai[0] = 0.f;
                ar[1] = shA[kk * LA + ty + 16]; ai[1] = 0.f;
            } else {
                float2 a0 = ((const float2*)shA)[kk * LA + ty];
                float2 a1 = ((const float2*)shA)[kk * LA + ty + 16];
                ar[0] = a0.x; ai[0] = a0.y;
                ar[1] = a1.x; ai[1] = a1.y;
            }
            float br[2], bi[2];
            if (BREALT) {
                float2 bv = *(const float2*)&shB[kk * LB + 2 * tx];  // 2 reals
                br[0] = bv.x; bi[0] = 0.f;
                br[1] = bv.y; bi[1] = 0.f;
            } else {
                float4 bv = *(const float4*)&((float2*)shB)[kk * LB + 2 * tx];
                br[0] = bv.x; bi[0] = bv.y;
                br[1] = bv.z; bi[1] = bv.w;
            }
#pragma unroll
            for (int mi = 0; mi < 2; mi++)
#pragma unroll
                for (int ni = 0; ni < 2; ni++) {
                    if (AREAL) {
                        acc[mi][ni][0] += ar[mi] * br[ni];
                        acc[mi][ni][1] += ar[mi] * bi[ni];
                    } else if (BREALT) {
                        acc[mi][ni][0] += ar[mi] * br[ni];
                        acc[mi][ni][1] += ai[mi] * br[ni];
                    } else {
                        acc[mi][ni][0] += ar[mi] * br[ni] - ai[mi] * bi[ni];
                        acc[mi][ni][1] += ar[mi] * bi[ni] + ai[mi] * br[ni];
                    }
                }
        }
        __syncthreads();
    }
    // ---- epilogue ----
#pragma unroll
    for (int mi = 0; mi < 2; mi++) {
        int m = m0 + ty + mi * 16;
        if (m >= M) continue;
#pragma unroll
        for (int ni = 0; ni < 2; ni++) {
            int n = n0 + 2 * tx + ni;
            if (n >= N) continue;
            size_t o = ((size_t)m * ldc + n) * 2;
            if (CADD) {
                Cb[o]     += scale * acc[mi][ni][0];
                Cb[o + 1] += scale * acc[mi][ni][1];
            } else {
                Cb[o]     = scale * acc[mi][ni][0];
                Cb[o + 1] = scale * acc[mi][ni][1];
            }
        }
    }
}

// --------------------------- complex 3x3 conv -------------------------------
// One output channel per thread; grid = (pix tiles, COUT, BB).
// forward: w[b][COUT][CIN][3][3]; adjoint: conj(w[b][CIN][COUT][3][3])^T(pq)
template<int CIN, int ADJ>
__global__ __launch_bounds__(256) void k_conv1(
        const float* __restrict__ in, float* __restrict__ out,
        const float* __restrict__ wre, const float* __restrict__ wim, int COUT) {
    const int b = blockIdx.z, o = blockIdx.y;
    __shared__ float wsr[CIN * 9], wsi[CIN * 9];
    const int tid = threadIdx.x;
    if (tid < CIN * 9) {
        int ci = tid / 9, k = tid % 9, p = k / 3, q = k % 3;
        int widx; float sg;
        if (!ADJ) { widx = ((b * COUT + o) * CIN + ci) * 9 + p * 3 + q; sg = 1.f; }
        else      { widx = ((b * CIN + ci) * COUT + o) * 9 + q * 3 + p; sg = -1.f; }
        wsr[tid] = wre[widx];
        wsi[tid] = sg * wim[widx];
    }
    __syncthreads();
    const int pix = blockIdx.x * 256 + tid;
    if (pix >= MM) return;
    const int y = pix / 257, x = pix % 257;
    const bool interior = (y >= 1) & (y <= 255) & (x >= 1) & (x <= 255);
    float ar = 0.f, ai = 0.f;
    const float2* ipb = (const float2*)in + (size_t)b * CIN * MM;
#pragma unroll
    for (int ci = 0; ci < CIN; ci++) {
        const float2* c = ipb + (size_t)ci * MM;
        if (interior) {
            const float2* r0 = c + (size_t)(y - 1) * 257 + (x - 1);
#pragma unroll
            for (int p = 0; p < 3; p++)
#pragma unroll
                for (int q = 0; q < 3; q++) {
                    float2 v = r0[p * 257 + q];
                    float wr = wsr[ci * 9 + p * 3 + q];
                    float wi = wsi[ci * 9 + p * 3 + q];
                    ar += v.x * wr - v.y * wi;
                    ai += v.x * wi + v.y * wr;
                }
        } else {
#pragma unroll
            for (int p = 0; p < 3; p++)
#pragma unroll
                for (int q = 0; q < 3; q++) {
                    int yy = y + p - 1, xx = x + q - 1;
                    if (yy < 0 || yy >= 257 || xx < 0 || xx >= 257) continue;
                    float2 v = c[(size_t)yy * 257 + xx];
                    float wr = wsr[ci * 9 + p * 3 + q];
                    float wi = wsi[ci * 9 + p * 3 + q];
                    ar += v.x * wr - v.y * wi;
                    ai += v.x * wi + v.y * wr;
                }
        }
    }
    float2* ob = (float2*)out + ((size_t)b * COUT + o) * MM + pix;
    *ob = make_float2(ar, ai);
}

// --------------------------- elementwise wt multiply ------------------------
__global__ void k_wtmul(const float* __restrict__ in, const float* __restrict__ wtr,
                        const float* __restrict__ wti, float* __restrict__ out) {
    int t = blockIdx.x * 256 + threadIdx.x;
    if (t >= BB * MM) return;
    float ar = in[2 * t], ai = in[2 * t + 1];
    float wr = wtr[t], wi = wti[t];
    out[2 * t] = ar * wr - ai * wi;
    out[2 * t + 1] = ar * wi + ai * wr;
}

// --------------------------- norm reduction ---------------------------------
__global__ void k_reduce(const float* __restrict__ r, const float* __restrict__ fr,
                         const float* __restrict__ fi, float* __restrict__ acc) {
    int b = blockIdx.y;
    int tid = threadIdx.x;
    float sr = 0.f, sf = 0.f;
    for (int idx = blockIdx.x * 256 + tid; idx < NN; idx += gridDim.x * 256) {
        const float* rp = r + ((size_t)b * NN + idx) * 2;
        float rx = rp[0], ry = rp[1];
        sr += rx * rx + ry * ry;
        float a = fr[(size_t)b * NN + idx], c = fi[(size_t)b * NN + idx];
        sf += a * a + c * c;
    }
    for (int off = 32; off > 0; off >>= 1) {
        sr += __shfl_down(sr, off);
        sf += __shfl_down(sf, off);
    }
    __shared__ float ssr[4], ssf[4];
    int wid = tid >> 6, lane = tid & 63;
    if (lane == 0) { ssr[wid] = sr; ssf[wid] = sf; }
    __syncthreads();
    if (tid == 0) {
        float tr = ssr[0] + ssr[1] + ssr[2] + ssr[3];
        float tf = ssf[0] + ssf[1] + ssf[2] + ssf[3];
        atomicAdd(&acc[2 * b], tr);
        atomicAdd(&acc[2 * b + 1], tf);
    }
}

__global__ void k_finalize(const float* __restrict__ acc, float* __restrict__ out) {
    if (threadIdx.x == 0 && blockIdx.x == 0) {
        float num = 0.f, den = 0.f;
        for (int b = 0; b < BB; b++) {
            num += sqrtf(acc[2 * b]);
            den += sqrtf(acc[2 * b + 1]);
        }
        out[0] = num / den;
    }
}

// ---------------------------------------------------------------------------
extern "C" void kernel_launch(void* const* d_in, const int* in_sizes, int n_in,
                              void* d_out, int out_size, void* d_ws, size_t ws_size,
                              hipStream_t stream) {
    (void)in_sizes; (void)n_in; (void)out_size; (void)ws_size;
    const float* fr  = (const float*)d_in[0];
    const float* fi  = (const float*)d_in[1];
    const float* kap = (const float*)d_in[2];
    const float* w1r = (const float*)d_in[3];
    const float* w1i = (const float*)d_in[4];
    const float* w2r = (const float*)d_in[5];
    const float* w2i = (const float*)d_in[6];
    const float* w3r = (const float*)d_in[7];
    const float* w3i = (const float*)d_in[8];
    const float* wtr = (const float*)d_in[9];
    const float* wti = (const float*)d_in[10];
    const int K = 3;   // epoch=81 -> (81-1)/40+1

    float* ws = (float*)d_ws;
    size_t off = 0;
    float* x0   = ws + off; off += (size_t)BB * NN * 2;
    float* x1   = ws + off; off += (size_t)BB * NN * 2;
    float* rb   = ws + off; off += (size_t)BB * NN * 2;
    float* kap2 = ws + off; off += (size_t)BB * NN;
    float* dinv = ws + off; off += (size_t)BB * NN;
    float* tA   = ws + off; off += (size_t)BB * MM * 2;
    float* tB   = ws + off; off += (size_t)BB * MM * 2;
    float* c4a  = ws + off; off += (size_t)BB * 4 * MM * 2;
    float* c4b  = ws + off; off += (size_t)BB * 4 * MM * 2;
    float* S    = ws + off; off += 257 * 256;
    float* W    = ws + off; off += 256 * 257 * 2;
    float* WT   = ws + off; off += 257 * 256 * 2;
    float* acc  = ws + off; off += 16;

    const long MB = (long)MM * 2;   // per-batch cplx matrix stride (floats)

    int sgrid = (BB * NN + 255) / 256;
    k_init<<<sgrid, 256, 0, stream>>>(kap, kap2, dinv, x0, acc);
    k_mats<<<(MSZ * MSZ + 255) / 256, 256, 0, stream>>>(S, W, WT);

    float* xc = x0;
    float* xo = x1;
    for (int it = 0; it < K; ++it) {
        for (int s = 0; s < 3; ++s) {
            k_step<<<sgrid, 256, 0, stream>>>(xc, xo, fr, fi, kap2, dinv, 0);
            float* t = xc; xc = xo; xo = t;
        }
        k_step<<<sgrid, 256, 0, stream>>>(xc, rb, fr, fi, kap2, dinv, 1);
        // DST pass 1: tA[u][p] = sum_m S[u][m] * rb[m][p]        (257x256x256)
        cgemm<1, 0, 0><<<dim3(8, 9, BB), 256, 0, stream>>>(
            S, rb, tA, 257, 256, 256, 256, 256, 256, 0, (long)NN * 2, MB, 1.f);
        // DST pass 2: tB[u][v] = C1 * sum_p tA[u][p] * S[v][p]   (257x257x256)
        cgemm<0, 1, 0><<<dim3(9, 9, BB), 256, 0, stream>>>(
            tA, S, tB, 257, 257, 256, 256, 256, 257, MB, 0, MB, C1F);
        // conv chain forward
        k_conv1<1, 0><<<dim3(259, 4, BB), 256, 0, stream>>>(tB, c4a, w1r, w1i, 4);
        k_conv1<4, 0><<<dim3(259, 4, BB), 256, 0, stream>>>(c4a, c4b, w2r, w2i, 4);
        k_conv1<4, 0><<<dim3(259, 1, BB), 256, 0, stream>>>(c4b, tA, w3r, w3i, 1);
        k_wtmul<<<(BB * MM + 255) / 256, 256, 0, stream>>>(tA, wtr, wti, tB);
        // conv chain adjoint
        k_conv1<1, 1><<<dim3(259, 4, BB), 256, 0, stream>>>(tB, c4a, w3r, w3i, 4);
        k_conv1<4, 1><<<dim3(259, 4, BB), 256, 0, stream>>>(c4a, c4b, w2r, w2i, 4);
        k_conv1<4, 1><<<dim3(259, 1, BB), 256, 0, stream>>>(c4b, tA, w1r, w1i, 1);
        // DFT pass 1: tB[k][v] = sum_u W[k][u] * tA[u][v]        (256x257x257)
        cgemm<0, 0, 0><<<dim3(9, 8, BB), 256, 0, stream>>>(
            W, tA, tB, 256, 257, 257, 257, 257, 257, 0, MB, MB, 1.f);
        // DFT pass 2 + add: xc[k][l] += sum_v tB[k][v] * WT[v][l] (256x256x257)
        cgemm<0, 0, 1><<<dim3(8, 8, BB), 256, 0, stream>>>(
            tB, WT, xc, 256, 256, 257, 257, 256, 256, MB, 0, (long)NN * 2, 1.f);
    }
    k_step<<<sgrid, 256, 0, stream>>>(xc, rb, fr, fi, kap2, dinv, 1);
    k_reduce<<<dim3(32, BB), 256, 0, stream>>>(rb, fr, fi, acc);
    k_finalize<<<1, 64, 0, stream>>>(acc, (float*)d_out);
}

// Round 5
// 817.765 us; speedup vs baseline: 1.8405x; 1.3154x over previous
//
#include <hip/hip_runtime.h>

// ---------------------------------------------------------------------------
// HyperFNS: Helmholtz Jacobi + FNS spectral correction, B=8, N=256, K=3.
// FFTs collapsed analytically into sine/DFT matrix products (split-K complex
// GEMM + reduce, DST symmetry quartered). Convs LDS-halo-tiled, wtmul fused.
// ---------------------------------------------------------------------------

#define BB 8
#define NN 65536          // 256*256
#define MM 66049          // 257*257

constexpr double PI_D    = 3.14159265358979323846;
constexpr double OMEGA_D = 40.0 * PI_D;           // N=256 -> omega = 40*pi
constexpr double H_D     = 1.0 / 255.0;
constexpr float  OMEGA2F = (float)(OMEGA_D * OMEGA_D);
constexpr float  BCVF    = (float)(2.0 * H_D * OMEGA_D);   // bc = i*BCVF
constexpr float  INVH2F  = 65025.0f;                        // 1/h^2 = 255^2
constexpr float  C1F     = (float)(-4.0 / (514.0 * 514.0)); // ifft2 odd-sym factor
constexpr float  TP514   = (float)(2.0 * PI_D / 514.0);

// --------------------------- init -------------------------------------------
__global__ void k_init(const float* __restrict__ kappa, float* __restrict__ kap2,
                       float* __restrict__ dinv, float* __restrict__ x0,
                       float* __restrict__ acc) {
    int t = blockIdx.x * 256 + threadIdx.x;
    if (t < BB * NN) {
        float k = kappa[t];
        float k2 = k * k;
        kap2[t] = k2;
        dinv[t] = 1.0f / (4.0f * INVH2F - OMEGA2F * k2);
        x0[2 * t] = 0.f; x0[2 * t + 1] = 0.f;
    }
    if (t < 16) acc[t] = 0.f;
}

// --------------------------- transform matrices -----------------------------
// S [u<257][m<256]  = sin(2*pi*(u-128)*(m+1)/514)   (only rows u<=128 used)
// W [k<256][u<257]  = (-1)^k * exp(-2*pi*i*k*(u+129)/514)
// WT[v<257][l<256]  = W[l][v]
__global__ void k_mats(float* __restrict__ S, float* __restrict__ W,
                       float* __restrict__ WT) {
    int t = blockIdx.x * 256 + threadIdx.x;
    if (t >= 257 * 257) return;
    int i = t / 257, j = t % 257;
    if (j < 256) {
        int a = (i - 128) * (j + 1);
        int m = ((a % 514) + 514) % 514;
        S[i * 256 + j] = sinf(m * TP514);
    }
    if (i < 256) {
        int tt = (i * (j + 129)) % 514;
        float cc = cosf(tt * TP514), ss = sinf(tt * TP514);
        float sg = (i & 1) ? -1.f : 1.f;
        W[(i * 257 + j) * 2] = sg * cc;
        W[(i * 257 + j) * 2 + 1] = -sg * ss;
    }
    if (j < 256) {
        int tt = (j * (i + 129)) % 514;
        float cc = cosf(tt * TP514), ss = sinf(tt * TP514);
        float sg = (j & 1) ? -1.f : 1.f;
        WT[(i * 256 + j) * 2] = sg * cc;
        WT[(i * 256 + j) * 2 + 1] = -sg * ss;
    }
}

// --------------------------- stencil: smooth / residual ---------------------
__global__ void k_step(const float* __restrict__ xin, float* __restrict__ out,
                       const float* __restrict__ fr, const float* __restrict__ fi,
                       const float* __restrict__ kap2, const float* __restrict__ dinv,
                       int mode) {
    int t = blockIdx.x * 256 + threadIdx.x;
    if (t >= BB * NN) return;
    int b = t >> 16;
    int ij = t & 65535;
    int i = ij >> 8, j = ij & 255;
    const float* xb = xin + (size_t)b * NN * 2;
    float xcr = xb[2 * ij], xci = xb[2 * ij + 1];
    float ur, ui, dr, di, lr, li, rr, ri;
    if (i > 0) { int n = ij - 256; ur = xb[2 * n]; ui = xb[2 * n + 1]; }
    else { int n = 256 + j; ur = xb[2 * n] - BCVF * xci; ui = xb[2 * n + 1] + BCVF * xcr; }
    if (i < 255) { int n = ij + 256; dr = xb[2 * n]; di = xb[2 * n + 1]; }
    else { int n = 254 * 256 + j; dr = xb[2 * n] - BCVF * xci; di = xb[2 * n + 1] + BCVF * xcr; }
    if (j > 0) { int n = ij - 1; lr = xb[2 * n]; li = xb[2 * n + 1]; }
    else { int n = i * 256 + 1; lr = xb[2 * n] - BCVF * xci; li = xb[2 * n + 1] + BCVF * xcr; }
    if (j < 255) { int n = ij + 1; rr = xb[2 * n]; ri = xb[2 * n + 1]; }
    else { int n = i * 256 + 254; rr = xb[2 * n] - BCVF * xci; ri = xb[2 * n + 1] + BCVF * xcr; }
    float k2 = kap2[t];
    float axr = (4.f * xcr - ur - dr - lr - rr) * INVH2F - OMEGA2F * k2 * xcr;
    float axi = (4.f * xci - ui - di - li - ri) * INVH2F - OMEGA2F * k2 * xci;
    float resr = fr[t] - axr, resi = fi[t] - axi;
    if (mode == 0) {
        float dv = dinv[t] * (2.0f / 3.0f);
        out[2 * t] = xcr + dv * resr;
        out[2 * t + 1] = xci + dv * resi;
    } else {
        out[2 * t] = resr;
        out[2 * t + 1] = resi;
    }
}

// --------------------------- split-K complex GEMM (partials) ----------------
// P[(b*4+s)][m][n] = sum_{k in chunk s} A[m][k]*B[k][n]   (no scale here)
// AREAL: A real, lda floats.  BREALT: B real transposed (B[k][n]=Bg[n*ldb+k]).
// Tile 64x64, BK=16, 256 threads, 4x4 cplx per thread. Grid z = batch*4+split.
template<int AREAL, int BREALT>
__global__ __launch_bounds__(256) void cgemm4(
        const float* __restrict__ A, const float* __restrict__ Bg,
        float* __restrict__ P, int M, int N, int K, int lda, int ldb,
        long aBatch, long bBatch) {
    constexpr int BK = 16;
    constexpr int LA = 66, LAr = 68, LB = 66, LBr = 68;
    __shared__ __align__(16) float shA[AREAL ? BK * LAr : BK * LA * 2];
    __shared__ __align__(16) float shB[BREALT ? BK * LBr : BK * LB * 2];

    const int tid = threadIdx.x;
    const int s = blockIdx.z & 3, b = blockIdx.z >> 2;
    const float* Ab = A + (size_t)b * aBatch;
    const float* Bb = Bg + (size_t)b * bBatch;
    const int Kq = (K + 3) >> 2;
    const int kbeg = s * Kq;
    const int kend = min(K, kbeg + Kq);

    const int m0 = blockIdx.y * 64;
    const int n0 = blockIdx.x * 64;
    const int ty = tid >> 4, tx = tid & 15;

    float accr[4][4], acci[4][4];
#pragma unroll
    for (int i = 0; i < 4; i++)
#pragma unroll
        for (int j = 0; j < 4; j++) { accr[i][j] = 0.f; acci[i][j] = 0.f; }

    for (int kb = kbeg; kb < kend; kb += BK) {
        // ---- A tile: 64m x 16k ----
        {
            int am = tid >> 2, ak = (tid & 3) * 4;
            int gm = m0 + am;
#pragma unroll
            for (int j = 0; j < 4; j++) {
                int gk = kb + ak + j;
                if (AREAL) {
                    float v = (gm < M && gk < kend) ? Ab[(size_t)gm * lda + gk] : 0.f;
                    shA[(ak + j) * LAr + am] = v;
                } else {
                    float2 v = make_float2(0.f, 0.f);
                    if (gm < M && gk < kend) v = ((const float2*)Ab)[(size_t)gm * lda + gk];
                    ((float2*)shA)[(ak + j) * LA + am] = v;
                }
            }
        }
        // ---- B tile: 16k x 64n ----
        if (BREALT) {
            int bn = tid >> 2, bk = (tid & 3) * 4;
            int gn = n0 + bn;
#pragma unroll
            for (int j = 0; j < 4; j++) {
                int gk = kb + bk + j;
                float v = (gn < N && gk < kend) ? Bb[(size_t)gn * ldb + gk] : 0.f;
                shB[(bk + j) * LBr + bn] = v;
            }
        } else {
            int bk = tid >> 4, bn = (tid & 15) * 4;
            int gk = kb + bk;
#pragma unroll
            for (int j = 0; j < 4; j++) {
                int gn = n0 + bn + j;
                float2 v = make_float2(0.f, 0.f);
                if (gk < kend && gn < N) v = ((const float2*)Bb)[(size_t)gk * ldb + gn];
                ((float2*)shB)[bk * LB + bn + j] = v;
            }
        }
        __syncthreads();
#pragma unroll
        for (int kk = 0; kk < BK; kk++) {
            float ar[4], ai[4], br[4], bi[4];
            if (AREAL) {
                float4 a0 = *(const float4*)&shA[kk * LAr + 4 * ty];
                ar[0] = a0.x; ar[1] = a0.y; ar[2] = a0.z; ar[3] = a0.w;
                ai[0] = ai[1] = ai[2] = ai[3] = 0.f;
            } else {
                float4 a0 = *(const float4*)&((const float2*)shA)[kk * LA + 4 * ty];
                float4 a1 = *(const float4*)&((const float2*)shA)[kk * LA + 4 * ty + 2];
                ar[0] = a0.x; ai[0] = a0.y; ar[1] = a0.z; ai[1] = a0.w;
                ar[2] = a1.x; ai[2] = a1.y; ar[3] = a1.z; ai[3] = a1.w;
            }
            if (BREALT) {
                float4 b0 = *(const float4*)&shB[kk * LBr + 4 * tx];
                br[0] = b0.x; br[1] = b0.y; br[2] = b0.z; br[3] = b0.w;
                bi[0] = bi[1] = bi[2] = bi[3] = 0.f;
            } else {
                float4 b0 = *(const float4*)&((const float2*)shB)[kk * LB + 4 * tx];
                float4 b1 = *(const float4*)&((const float2*)shB)[kk * LB + 4 * tx + 2];
                br[0] = b0.x; bi[0] = b0.y; br[1] = b0.z; bi[1] = b0.w;
                br[2] = b1.x; bi[2] = b1.y; br[3] = b1.z; bi[3] = b1.w;
            }
#pragma unroll
            for (int mi = 0; mi < 4; mi++)
#pragma unroll
                for (int ni = 0; ni < 4; ni++) {
                    if (AREAL) {
                        accr[mi][ni] += ar[mi] * br[ni];
                        acci[mi][ni] += ar[mi] * bi[ni];
                    } else if (BREALT) {
                        accr[mi][ni] += ar[mi] * br[ni];
                        acci[mi][ni] += ai[mi] * br[ni];
                    } else {
                        accr[mi][ni] += ar[mi] * br[ni] - ai[mi] * bi[ni];
                        acci[mi][ni] += ar[mi] * bi[ni] + ai[mi] * br[ni];
                    }
                }
        }
        __syncthreads();
    }
    // ---- write compact partial ----
    float* Pb = P + (size_t)(b * 4 + s) * M * N * 2;
#pragma unroll
    for (int mi = 0; mi < 4; mi++) {
        int mc = m0 + 4 * ty + mi;
        if (mc >= M) continue;
#pragma unroll
        for (int ni = 0; ni < 4; ni++) {
            int nc = n0 + 4 * tx + ni;
            if (nc >= N) continue;
            size_t o = ((size_t)mc * N + nc) * 2;
            Pb[o] = accr[mi][ni]; Pb[o + 1] = acci[mi][ni];
        }
    }
}

// --------------------------- partial reduce (+scale, CADD, mirror) ----------
// MIRROR: input quadrant Mc=Nc=129, output 257x257 with odd symmetry.
template<int CADD, int MIRROR>
__global__ __launch_bounds__(256) void k_reduceP(
        const float* __restrict__ P, float* __restrict__ C,
        int Mc, int Nc, int ldc, long cBatch, float scale) {
    int b = blockIdx.y;
    int t = blockIdx.x * 256 + threadIdx.x;
    int tot = Mc * Nc;
    if (t >= tot) return;
    const float* Pb = P + (size_t)b * 4 * tot * 2;
    float vr = 0.f, vi = 0.f;
#pragma unroll
    for (int s = 0; s < 4; s++) {
        vr += Pb[((size_t)s * tot + t) * 2];
        vi += Pb[((size_t)s * tot + t) * 2 + 1];
    }
    vr *= scale; vi *= scale;
    int mc = t / Nc, nc = t % Nc;
    float* Cb = C + (size_t)b * cBatch;
    if (MIRROR) {
        int mm = 256 - mc, nm = 256 - nc;
        Cb[((size_t)mc * 257 + nc) * 2] = vr;  Cb[((size_t)mc * 257 + nc) * 2 + 1] = vi;
        Cb[((size_t)mm * 257 + nc) * 2] = -vr; Cb[((size_t)mm * 257 + nc) * 2 + 1] = -vi;
        Cb[((size_t)mc * 257 + nm) * 2] = -vr; Cb[((size_t)mc * 257 + nm) * 2 + 1] = -vi;
        Cb[((size_t)mm * 257 + nm) * 2] = vr;  Cb[((size_t)mm * 257 + nm) * 2 + 1] = vi;
    } else {
        size_t o = ((size_t)mc * ldc + nc) * 2;
        if (CADD) { Cb[o] += vr; Cb[o + 1] += vi; }
        else      { Cb[o] = vr;  Cb[o + 1] = vi; }
    }
}

// --------------------------- LDS-halo-tiled complex 3x3 conv ----------------
// 32x8 pixel tile, all CIN staged, all COUT per thread. WTM fuses *wt.
template<int CIN, int COUT, int ADJ, int WTM>
__global__ __launch_bounds__(256) void k_convT(
        const float* __restrict__ in, float* __restrict__ out,
        const float* __restrict__ wre, const float* __restrict__ wim,
        const float* __restrict__ wtr, const float* __restrict__ wti) {
    const int b = blockIdx.y;
    const int bx = blockIdx.x % 9, by = blockIdx.x / 9;
    const int x0 = bx * 32, y0 = by * 8;
    __shared__ float2 sh[CIN][10][34];
    __shared__ float wsr[COUT * CIN * 9], wsi[COUT * CIN * 9];
    const int tid = threadIdx.x;
    if (tid < COUT * CIN * 9) {
        int o = tid / (CIN * 9), rem = tid % (CIN * 9);
        int ci = rem / 9, k = rem % 9, p = k / 3, q = k % 3;
        int widx; float sg;
        if (!ADJ) { widx = ((b * COUT + o) * CIN + ci) * 9 + p * 3 + q; sg = 1.f; }
        else      { widx = ((b * CIN + ci) * COUT + o) * 9 + q * 3 + p; sg = -1.f; }
        wsr[tid] = wre[widx];
        wsi[tid] = sg * wim[widx];
    }
    const float2* ipb = (const float2*)in + (size_t)b * CIN * MM;
    for (int i = tid; i < CIN * 340; i += 256) {
        int ci = i / 340, r = i % 340;
        int ly = r / 34, lx = r % 34;
        int gy = y0 + ly - 1, gx = x0 + lx - 1;
        float2 v = make_float2(0.f, 0.f);
        if (gy >= 0 && gy < 257 && gx >= 0 && gx < 257)
            v = ipb[(size_t)ci * MM + (size_t)gy * 257 + gx];
        sh[ci][ly][lx] = v;
    }
    __syncthreads();
    const int lx = tid & 31, ly = tid >> 5;
    const int x = x0 + lx, y = y0 + ly;
    if (x >= 257 || y >= 257) return;
    float accr[COUT], acci[COUT];
#pragma unroll
    for (int o = 0; o < COUT; o++) { accr[o] = 0.f; acci[o] = 0.f; }
#pragma unroll
    for (int ci = 0; ci < CIN; ci++)
#pragma unroll
        for (int p = 0; p < 3; p++)
#pragma unroll
            for (int q = 0; q < 3; q++) {
                float2 v = sh[ci][ly + p][lx + q];
#pragma unroll
                for (int o = 0; o < COUT; o++) {
                    float wr = wsr[(o * CIN + ci) * 9 + p * 3 + q];
                    float wi = wsi[(o * CIN + ci) * 9 + p * 3 + q];
                    accr[o] += v.x * wr - v.y * wi;
                    acci[o] += v.x * wi + v.y * wr;
                }
            }
    if (WTM) {
        float wr = wtr[(size_t)b * MM + (size_t)y * 257 + x];
        float wi = wti[(size_t)b * MM + (size_t)y * 257 + x];
        float r0 = accr[0] * wr - acci[0] * wi;
        float i0 = accr[0] * wi + acci[0] * wr;
        accr[0] = r0; acci[0] = i0;
    }
    float2* ob = (float2*)out + (size_t)b * COUT * MM + (size_t)y * 257 + x;
#pragma unroll
    for (int o = 0; o < COUT; o++)
        ob[(size_t)o * MM] = make_float2(accr[o], acci[o]);
}

// --------------------------- norm reduction ---------------------------------
__global__ void k_reduce(const float* __restrict__ r, const float* __restrict__ fr,
                         const float* __restrict__ fi, float* __restrict__ acc) {
    int b = blockIdx.y;
    int tid = threadIdx.x;
    float sr = 0.f, sf = 0.f;
    for (int idx = blockIdx.x * 256 + tid; idx < NN; idx += gridDim.x * 256) {
        const float* rp = r + ((size_t)b * NN + idx) * 2;
        float rx = rp[0], ry = rp[1];
        sr += rx * rx + ry * ry;
        float a = fr[(size_t)b * NN + idx], c = fi[(size_t)b * NN + idx];
        sf += a * a + c * c;
    }
    for (int off = 32; off > 0; off >>= 1) {
        sr += __shfl_down(sr, off);
        sf += __shfl_down(sf, off);
    }
    __shared__ float ssr[4], ssf[4];
    int wid = tid >> 6, lane = tid & 63;
    if (lane == 0) { ssr[wid] = sr; ssf[wid] = sf; }
    __syncthreads();
    if (tid == 0) {
        float tr = ssr[0] + ssr[1] + ssr[2] + ssr[3];
        float tf = ssf[0] + ssf[1] + ssf[2] + ssf[3];
        atomicAdd(&acc[2 * b], tr);
        atomicAdd(&acc[2 * b + 1], tf);
    }
}

__global__ void k_finalize(const float* __restrict__ acc, float* __restrict__ out) {
    if (threadIdx.x == 0 && blockIdx.x == 0) {
        float num = 0.f, den = 0.f;
        for (int b = 0; b < BB; b++) {
            num += sqrtf(acc[2 * b]);
            den += sqrtf(acc[2 * b + 1]);
        }
        out[0] = num / den;
    }
}

// ---------------------------------------------------------------------------
extern "C" void kernel_launch(void* const* d_in, const int* in_sizes, int n_in,
                              void* d_out, int out_size, void* d_ws, size_t ws_size,
                              hipStream_t stream) {
    (void)in_sizes; (void)n_in; (void)out_size; (void)ws_size;
    const float* fr  = (const float*)d_in[0];
    const float* fi  = (const float*)d_in[1];
    const float* kap = (const float*)d_in[2];
    const float* w1r = (const float*)d_in[3];
    const float* w1i = (const float*)d_in[4];
    const float* w2r = (const float*)d_in[5];
    const float* w2i = (const float*)d_in[6];
    const float* w3r = (const float*)d_in[7];
    const float* w3i = (const float*)d_in[8];
    const float* wtr = (const float*)d_in[9];
    const float* wti = (const float*)d_in[10];
    const int K = 3;   // epoch=81 -> (81-1)/40+1

    float* ws = (float*)d_ws;
    size_t off = 0;
    float* x0   = ws + off; off += (size_t)BB * NN * 2;
    float* x1   = ws + off; off += (size_t)BB * NN * 2;
    float* rb   = ws + off; off += (size_t)BB * NN * 2;
    float* kap2 = ws + off; off += (size_t)BB * NN;
    float* dinv = ws + off; off += (size_t)BB * NN;
    float* tA   = ws + off; off += (size_t)BB * MM * 2;
    float* tB   = ws + off; off += (size_t)BB * MM * 2;
    float* c4a  = ws + off; off += (size_t)BB * 4 * MM * 2;   // partial / conv buf
    float* c4b  = ws + off; off += (size_t)BB * 4 * MM * 2;
    float* S    = ws + off; off += 257 * 256;
    float* W    = ws + off; off += 256 * 257 * 2;
    float* WT   = ws + off; off += 257 * 256 * 2;
    float* acc  = ws + off; off += 16;

    int sgrid = (BB * NN + 255) / 256;
    k_init<<<sgrid, 256, 0, stream>>>(kap, kap2, dinv, x0, acc);
    k_mats<<<(257 * 257 + 255) / 256, 256, 0, stream>>>(S, W, WT);

    float* xc = x0;
    float* xo = x1;
    for (int it = 0; it < K; ++it) {
        for (int s = 0; s < 3; ++s) {
            k_step<<<sgrid, 256, 0, stream>>>(xc, xo, fr, fi, kap2, dinv, 0);
            float* t = xc; xc = xo; xo = t;
        }
        k_step<<<sgrid, 256, 0, stream>>>(xc, rb, fr, fi, kap2, dinv, 1);

        // DST1: tA[u<129][p<256] = sum_m S[u][m]*rb[m][p]
        cgemm4<1, 0><<<dim3(4, 3, 32), 256, 0, stream>>>(
            S, rb, c4a, 129, 256, 256, 256, 256, 0, (long)NN * 2);
        k_reduceP<0, 0><<<dim3(129, BB), 256, 0, stream>>>(
            c4a, tA, 129, 256, 256, (long)129 * 256 * 2, 1.f);

        // DST2 quadrant + mirror: tB = C1 * tA * S^T  (full 257x257 out)
        cgemm4<0, 1><<<dim3(3, 3, 32), 256, 0, stream>>>(
            tA, S, c4a, 129, 129, 256, 256, 256, (long)129 * 256 * 2, 0);
        k_reduceP<0, 1><<<dim3(66, BB), 256, 0, stream>>>(
            c4a, tB, 129, 129, 257, (long)MM * 2, C1F);

        // conv chain forward (+wt fused into third)
        k_convT<1, 4, 0, 0><<<dim3(297, BB), 256, 0, stream>>>(tB, c4b, w1r, w1i, fr, fi);
        k_convT<4, 4, 0, 0><<<dim3(297, BB), 256, 0, stream>>>(c4b, c4a, w2r, w2i, fr, fi);
        k_convT<4, 1, 0, 1><<<dim3(297, BB), 256, 0, stream>>>(c4a, tA, w3r, w3i, wtr, wti);
        // conv chain adjoint
        k_convT<1, 4, 1, 0><<<dim3(297, BB), 256, 0, stream>>>(tA, c4b, w3r, w3i, fr, fi);
        k_convT<4, 4, 1, 0><<<dim3(297, BB), 256, 0, stream>>>(c4b, c4a, w2r, w2i, fr, fi);
        k_convT<4, 1, 1, 0><<<dim3(297, BB), 256, 0, stream>>>(c4a, tA, w1r, w1i, fr, fi);

        // DFT1: tB[k<256][v<257] = sum_u W[k][u]*tA[u][v]
        cgemm4<0, 0><<<dim3(5, 4, 32), 256, 0, stream>>>(
            W, tA, c4a, 256, 257, 257, 257, 257, 0, (long)MM * 2);
        k_reduceP<0, 0><<<dim3(257, BB), 256, 0, stream>>>(
            c4a, tB, 256, 257, 257, (long)MM * 2, 1.f);

        // DFT2 + add: xc[k][l] += sum_v tB[k][v]*WT[v][l]
        cgemm4<0, 0><<<dim3(4, 4, 32), 256, 0, stream>>>(
            tB, WT, c4a, 256, 256, 257, 257, 256, (long)MM * 2, 0);
        k_reduceP<1, 0><<<dim3(256, BB), 256, 0, stream>>>(
            c4a, xc, 256, 256, 256, (long)NN * 2, 1.f);
    }
    k_step<<<sgrid, 256, 0, stream>>>(xc, rb, fr, fi, kap2, dinv, 1);
    k_reduce<<<dim3(32, BB), 256, 0, stream>>>(rb, fr, fi, acc);
    k_finalize<<<1, 64, 0, stream>>>(acc, (float*)d_out);
}

// Round 6
// 781.966 us; speedup vs baseline: 1.9248x; 1.0458x over previous
//
#include <hip/hip_runtime.h>

// ---------------------------------------------------------------------------
// HyperFNS: Helmholtz Jacobi + FNS spectral correction, B=8, N=256, K=3.
// Transforms = complex GEMMs on MFMA (bf16 split-precision, K-interleaved
// complex). Convs LDS-halo-tiled. Epilogue fuses scale/add/mirror.
// ---------------------------------------------------------------------------

#define BB 8
#define NN 65536          // 256*256
#define MM 66049          // 257*257

constexpr double PI_D    = 3.14159265358979323846;
constexpr double OMEGA_D = 40.0 * PI_D;
constexpr double H_D     = 1.0 / 255.0;
constexpr float  OMEGA2F = (float)(OMEGA_D * OMEGA_D);
constexpr float  BCVF    = (float)(2.0 * H_D * OMEGA_D);
constexpr float  INVH2F  = 65025.0f;
constexpr float  C1F     = (float)(-4.0 / (514.0 * 514.0));
constexpr float  TP514   = (float)(2.0 * PI_D / 514.0);

typedef __attribute__((ext_vector_type(8))) short short8v;
typedef __attribute__((ext_vector_type(4))) float f32x4;

// --------------------------- bf16 split helpers -----------------------------
__device__ inline unsigned short bfh(float x) {
    unsigned u = __float_as_uint(x);
    unsigned r = (u + 0x7FFFu + ((u >> 16) & 1u)) >> 16;
    return (unsigned short)r;
}
__device__ inline float bfh_f(unsigned short h) {
    return __uint_as_float(((unsigned)h) << 16);
}
__device__ inline void bsplit(float x, unsigned short& h, unsigned short& l) {
    h = bfh(x);
    l = bfh(x - bfh_f(h));
}

// --------------------------- init -------------------------------------------
__global__ void k_init(const float* __restrict__ kappa, float* __restrict__ kap2,
                       float* __restrict__ dinv, float* __restrict__ x0,
                       float* __restrict__ acc) {
    int t = blockIdx.x * 256 + threadIdx.x;
    if (t < BB * NN) {
        float k = kappa[t];
        float k2 = k * k;
        kap2[t] = k2;
        dinv[t] = 1.0f / (4.0f * INVH2F - OMEGA2F * k2);
        x0[2 * t] = 0.f; x0[2 * t + 1] = 0.f;
    }
    if (t < 16) acc[t] = 0.f;
}

// --------------------------- transform matrices (fp32) ----------------------
// S [u<257][m<256] = sin(2*pi*(u-128)*(m+1)/514)
// W [k<256][u<257] = (-1)^k * exp(-2*pi*i*k*(u+129)/514)
__global__ void k_mats(float* __restrict__ S, float* __restrict__ W) {
    int t = blockIdx.x * 256 + threadIdx.x;
    if (t >= 257 * 257) return;
    int i = t / 257, j = t % 257;
    if (j < 256) {
        int a = (i - 128) * (j + 1);
        int m = ((a % 514) + 514) % 514;
        S[i * 256 + j] = sinf(m * TP514);
    }
    if (i < 256) {
        int tt = (i * (j + 129)) % 514;
        float cc = cosf(tt * TP514), ss = sinf(tt * TP514);
        float sg = (i & 1) ? -1.f : 1.f;
        W[(i * 257 + j) * 2] = sg * cc;
        W[(i * 257 + j) * 2 + 1] = -sg * ss;
    }
}

// --------------------------- static bf16 packs ------------------------------
// sA1[u<129][512]: even=S[u][m], odd=0    (DST1 A1; also DST2 B)
// sA2[u<129][512]: even=0, odd=S[u][m]    (DST1 A2)
// wA1[k<256][544]: even=Wr, odd=-Wi ; wA2: even=Wi, odd=Wr   (DFT1 A)
// wB [l<256][544]: even=Wr[l][v], odd=Wi[l][v]               (DFT2 B = WT)
__global__ void k_packstat(const float* __restrict__ S, const float* __restrict__ W,
        unsigned short* sA1h, unsigned short* sA1l,
        unsigned short* sA2h, unsigned short* sA2l,
        unsigned short* wA1h, unsigned short* wA1l,
        unsigned short* wA2h, unsigned short* wA2l,
        unsigned short* wBh,  unsigned short* wBl) {
    int t = blockIdx.x * 256 + threadIdx.x;
    if (t >= 256 * 544) return;
    int i = t / 544, c = t % 544;
    // W zone
    {
        unsigned short h1 = 0, l1 = 0, h2 = 0, l2 = 0, hb = 0, lb = 0;
        if (c < 514) {
            int u = c >> 1;
            float wr = W[(i * 257 + u) * 2];
            float wi = W[(i * 257 + u) * 2 + 1];
            if ((c & 1) == 0) {
                bsplit(wr, h1, l1); bsplit(wi, h2, l2); bsplit(wr, hb, lb);
            } else {
                bsplit(-wi, h1, l1); bsplit(wr, h2, l2); bsplit(wi, hb, lb);
            }
        }
        size_t o = (size_t)i * 544 + c;
        wA1h[o] = h1; wA1l[o] = l1;
        wA2h[o] = h2; wA2l[o] = l2;
        wBh[o] = hb;  wBl[o] = lb;
    }
    // S zone
    if (i < 129 && c < 512) {
        int m = c >> 1;
        float s = S[i * 256 + m];
        unsigned short hs, ls;
        bsplit(s, hs, ls);
        size_t o = (size_t)i * 512 + c;
        if ((c & 1) == 0) { sA1h[o] = hs; sA1l[o] = ls; sA2h[o] = 0; sA2l[o] = 0; }
        else              { sA1h[o] = 0;  sA1l[o] = 0;  sA2h[o] = hs; sA2l[o] = ls; }
    }
}

// --------------------------- stencil: smooth / residual ---------------------
__global__ void k_step(const float* __restrict__ xin, float* __restrict__ out,
                       const float* __restrict__ fr, const float* __restrict__ fi,
                       const float* __restrict__ kap2, const float* __restrict__ dinv,
                       int mode) {
    int t = blockIdx.x * 256 + threadIdx.x;
    if (t >= BB * NN) return;
    int b = t >> 16;
    int ij = t & 65535;
    int i = ij >> 8, j = ij & 255;
    const float* xb = xin + (size_t)b * NN * 2;
    float xcr = xb[2 * ij], xci = xb[2 * ij + 1];
    float ur, ui, dr, di, lr, li, rr, ri;
    if (i > 0) { int n = ij - 256; ur = xb[2 * n]; ui = xb[2 * n + 1]; }
    else { int n = 256 + j; ur = xb[2 * n] - BCVF * xci; ui = xb[2 * n + 1] + BCVF * xcr; }
    if (i < 255) { int n = ij + 256; dr = xb[2 * n]; di = xb[2 * n + 1]; }
    else { int n = 254 * 256 + j; dr = xb[2 * n] - BCVF * xci; di = xb[2 * n + 1] + BCVF * xcr; }
    if (j > 0) { int n = ij - 1; lr = xb[2 * n]; li = xb[2 * n + 1]; }
    else { int n = i * 256 + 1; lr = xb[2 * n] - BCVF * xci; li = xb[2 * n + 1] + BCVF * xcr; }
    if (j < 255) { int n = ij + 1; rr = xb[2 * n]; ri = xb[2 * n + 1]; }
    else { int n = i * 256 + 254; rr = xb[2 * n] - BCVF * xci; ri = xb[2 * n + 1] + BCVF * xcr; }
    float k2 = kap2[t];
    float axr = (4.f * xcr - ur - dr - lr - rr) * INVH2F - OMEGA2F * k2 * xcr;
    float axi = (4.f * xci - ui - di - li - ri) * INVH2F - OMEGA2F * k2 * xci;
    float resr = fr[t] - axr, resi = fi[t] - axi;
    if (mode == 0) {
        float dv = dinv[t] * (2.0f / 3.0f);
        out[2 * t] = xcr + dv * resr;
        out[2 * t + 1] = xci + dv * resi;
    } else {
        out[2 * t] = resr;
        out[2 * t + 1] = resi;
    }
}

// --------------------------- data pack: straight (A-side) -------------------
// in cplx [M][ldin] -> A1=[r,-i], A2=[i,r] interleaved along K' (KP padded)
__global__ __launch_bounds__(256) void k_packS(
        const float* __restrict__ in, int M, int Kin, int ldin, int KP,
        long inStrF, unsigned short* __restrict__ A1h, unsigned short* __restrict__ A1l,
        unsigned short* __restrict__ A2h, unsigned short* __restrict__ A2l, long outStr) {
    int b = blockIdx.z;
    int t = blockIdx.x * 256 + threadIdx.x;
    int kp2 = KP >> 1;
    int tot = M * kp2;
    if (t >= tot) return;
    int m = t / kp2, p = t % kp2;
    float vr = 0.f, vi = 0.f;
    if (p < Kin) {
        size_t ii = (size_t)b * inStrF + ((size_t)m * ldin + p) * 2;
        vr = in[ii]; vi = in[ii + 1];
    }
    unsigned short hr, lr, hi_, li_;
    bsplit(vr, hr, lr); bsplit(vi, hi_, li_);
    size_t o = (size_t)b * outStr + (size_t)m * KP + 2 * p;
    A1h[o] = hr;              A1h[o + 1] = hi_ ^ 0x8000;
    A1l[o] = lr;              A1l[o + 1] = li_ ^ 0x8000;
    A2h[o] = hi_;             A2h[o + 1] = hr;
    A2l[o] = li_;             A2l[o + 1] = lr;
}

// --------------------------- data pack: transpose (B-side) ------------------
// Bt[n][2u]=in[u][n].re, Bt[n][2u+1]=in[u][n].im  (zero-pad u>=Min, k>=2*Min)
__global__ __launch_bounds__(256) void k_packT(
        const float* __restrict__ in, int Min, int Nin, int KP,
        long inStrF2, unsigned short* __restrict__ Bh, unsigned short* __restrict__ Bl,
        long outStr) {
    int b = blockIdx.z;
    int n0 = blockIdx.x * 32, u0 = blockIdx.y * 32;
    __shared__ float2 lds[32][33];
    int tid = threadIdx.x;
    int r = tid >> 5, c = tid & 31;
    const float2* ip = (const float2*)in + (size_t)b * inStrF2;
    for (int rr = r; rr < 32; rr += 8) {
        int u = u0 + rr, n = n0 + c;
        float2 v = make_float2(0.f, 0.f);
        if (u < Min && n < Nin) v = ip[(size_t)u * Nin + n];
        lds[rr][c] = v;
    }
    __syncthreads();
    int tn = tid >> 3, tu4 = (tid & 7) * 4;
    int n = n0 + tn;
    if (n >= Nin) return;
    if (u0 + tu4 + 4 > (KP >> 1)) return;
    unsigned short hs[8], ls[8];
#pragma unroll
    for (int j = 0; j < 4; j++) {
        float2 v = lds[tu4 + j][tn];
        bsplit(v.x, hs[2 * j], ls[2 * j]);
        bsplit(v.y, hs[2 * j + 1], ls[2 * j + 1]);
    }
    size_t o = (size_t)b * outStr + (size_t)n * KP + 2 * (u0 + tu4);
    *(ushort4*)&Bh[o]     = make_ushort4(hs[0], hs[1], hs[2], hs[3]);
    *(ushort4*)&Bh[o + 4] = make_ushort4(hs[4], hs[5], hs[6], hs[7]);
    *(ushort4*)&Bl[o]     = make_ushort4(ls[0], ls[1], ls[2], ls[3]);
    *(ushort4*)&Bl[o + 4] = make_ushort4(ls[4], ls[5], ls[6], ls[7]);
}

// --------------------------- MFMA complex GEMM ------------------------------
// C[m][n] = scale * sum_k' A{1,2}[m][k']*B[k']  (split bf16: hh + hl + lh)
// EPI: 0 = store, 1 = add, 2 = mirror-store (odd symmetry, 257x257, scale)
template<int EPI>
__global__ __launch_bounds__(256) void mgemm(
        const unsigned short* __restrict__ A1h, const unsigned short* __restrict__ A1l,
        const unsigned short* __restrict__ A2h, const unsigned short* __restrict__ A2l,
        const unsigned short* __restrict__ Bh,  const unsigned short* __restrict__ Bl,
        float* __restrict__ C, int M, int N, int KP, int ldc,
        long aStr, long bStr, long cStrF2, float scale) {
    __shared__ unsigned short shA1h[1024], shA1l[1024], shA2h[1024], shA2l[1024];
    __shared__ unsigned short shBh[1024], shBl[1024];
    const int tid = threadIdx.x;
    const int b = blockIdx.z;
    const unsigned short* pA1h = A1h + (size_t)b * aStr;
    const unsigned short* pA1l = A1l + (size_t)b * aStr;
    const unsigned short* pA2h = A2h + (size_t)b * aStr;
    const unsigned short* pA2l = A2l + (size_t)b * aStr;
    const unsigned short* pBh  = Bh + (size_t)b * bStr;
    const unsigned short* pBl  = Bl + (size_t)b * bStr;
    const int m0 = blockIdx.y * 32, n0 = blockIdx.x * 32;
    const int wave = tid >> 6, lane = tid & 63;
    const int wm = wave >> 1, wn = wave & 1;
    const int srow = tid >> 3, scol = (tid & 7) * 4;

    f32x4 accr = {0.f, 0.f, 0.f, 0.f}, acci = {0.f, 0.f, 0.f, 0.f};
    const ushort4 z4 = make_ushort4(0, 0, 0, 0);
    const int nks = KP >> 5;
    for (int ks = 0; ks < nks; ks++) {
        const int kb = ks * 32;
        {
            int gm = m0 + srow;
            bool va = gm < M;
            size_t ao = (size_t)gm * KP + kb + scol;
            int so = srow * 32 + scol;
            *(ushort4*)&shA1h[so] = va ? *(const ushort4*)&pA1h[ao] : z4;
            *(ushort4*)&shA1l[so] = va ? *(const ushort4*)&pA1l[ao] : z4;
            *(ushort4*)&shA2h[so] = va ? *(const ushort4*)&pA2h[ao] : z4;
            *(ushort4*)&shA2l[so] = va ? *(const ushort4*)&pA2l[ao] : z4;
            int gn = n0 + srow;
            bool vb = gn < N;
            size_t bo = (size_t)gn * KP + kb + scol;
            *(ushort4*)&shBh[so] = vb ? *(const ushort4*)&pBh[bo] : z4;
            *(ushort4*)&shBl[so] = vb ? *(const ushort4*)&pBl[bo] : z4;
        }
        __syncthreads();
        const int ar = (wm * 16 + (lane & 15)) * 32 + ((lane >> 4) << 3);
        const int br = (wn * 16 + (lane & 15)) * 32 + ((lane >> 4) << 3);
        short8v a1h = *(const short8v*)&shA1h[ar];
        short8v a1l = *(const short8v*)&shA1l[ar];
        short8v a2h = *(const short8v*)&shA2h[ar];
        short8v a2l = *(const short8v*)&shA2l[ar];
        short8v bh  = *(const short8v*)&shBh[br];
        short8v bl  = *(const short8v*)&shBl[br];
        accr = __builtin_amdgcn_mfma_f32_16x16x32_bf16(a1h, bh, accr, 0, 0, 0);
        accr = __builtin_amdgcn_mfma_f32_16x16x32_bf16(a1l, bh, accr, 0, 0, 0);
        accr = __builtin_amdgcn_mfma_f32_16x16x32_bf16(a1h, bl, accr, 0, 0, 0);
        acci = __builtin_amdgcn_mfma_f32_16x16x32_bf16(a2h, bh, acci, 0, 0, 0);
        acci = __builtin_amdgcn_mfma_f32_16x16x32_bf16(a2l, bh, acci, 0, 0, 0);
        acci = __builtin_amdgcn_mfma_f32_16x16x32_bf16(a2h, bl, acci, 0, 0, 0);
        __syncthreads();
    }
    float* Cb = C + (size_t)b * cStrF2 * 2;
    const int col = n0 + wn * 16 + (lane & 15);
    const int rbase = m0 + wm * 16 + ((lane >> 4) << 2);
#pragma unroll
    for (int i = 0; i < 4; i++) {
        int row = rbase + i;
        if (row >= M || col >= N) continue;
        float vr = scale * accr[i], vi = scale * acci[i];
        if (EPI == 2) {
            int mm = 256 - row, nm = 256 - col;
            Cb[((size_t)row * 257 + col) * 2] = vr;  Cb[((size_t)row * 257 + col) * 2 + 1] = vi;
            Cb[((size_t)mm * 257 + col) * 2] = -vr;  Cb[((size_t)mm * 257 + col) * 2 + 1] = -vi;
            Cb[((size_t)row * 257 + nm) * 2] = -vr;  Cb[((size_t)row * 257 + nm) * 2 + 1] = -vi;
            Cb[((size_t)mm * 257 + nm) * 2] = vr;    Cb[((size_t)mm * 257 + nm) * 2 + 1] = vi;
        } else {
            size_t o = ((size_t)row * ldc + col) * 2;
            if (EPI == 1) { Cb[o] += vr; Cb[o + 1] += vi; }
            else          { Cb[o] = vr;  Cb[o + 1] = vi; }
        }
    }
}

// --------------------------- LDS-halo-tiled complex 3x3 conv ----------------
template<int CIN, int COUT, int ADJ, int WTM>
__global__ __launch_bounds__(256) void k_convT(
        const float* __restrict__ in, float* __restrict__ out,
        const float* __restrict__ wre, const float* __restrict__ wim,
        const float* __restrict__ wtr, const float* __restrict__ wti) {
    const int b = blockIdx.y;
    const int bx = blockIdx.x % 9, by = blockIdx.x / 9;
    const int x0 = bx * 32, y0 = by * 8;
    __shared__ float2 sh[CIN][10][34];
    __shared__ float wsr[COUT * CIN * 9], wsi[COUT * CIN * 9];
    const int tid = threadIdx.x;
    if (tid < COUT * CIN * 9) {
        int o = tid / (CIN * 9), rem = tid % (CIN * 9);
        int ci = rem / 9, k = rem % 9, p = k / 3, q = k % 3;
        int widx; float sg;
        if (!ADJ) { widx = ((b * COUT + o) * CIN + ci) * 9 + p * 3 + q; sg = 1.f; }
        else      { widx = ((b * CIN + ci) * COUT + o) * 9 + q * 3 + p; sg = -1.f; }
        wsr[tid] = wre[widx];
        wsi[tid] = sg * wim[widx];
    }
    const float2* ipb = (const float2*)in + (size_t)b * CIN * MM;
    for (int i = tid; i < CIN * 340; i += 256) {
        int ci = i / 340, r = i % 340;
        int ly = r / 34, lx = r % 34;
        int gy = y0 + ly - 1, gx = x0 + lx - 1;
        float2 v = make_float2(0.f, 0.f);
        if (gy >= 0 && gy < 257 && gx >= 0 && gx < 257)
            v = ipb[(size_t)ci * MM + (size_t)gy * 257 + gx];
        sh[ci][ly][lx] = v;
    }
    __syncthreads();
    const int lx = tid & 31, ly = tid >> 5;
    const int x = x0 + lx, y = y0 + ly;
    if (x >= 257 || y >= 257) return;
    float accr[COUT], acci[COUT];
#pragma unroll
    for (int o = 0; o < COUT; o++) { accr[o] = 0.f; acci[o] = 0.f; }
#pragma unroll
    for (int ci = 0; ci < CIN; ci++)
#pragma unroll
        for (int p = 0; p < 3; p++)
#pragma unroll
            for (int q = 0; q < 3; q++) {
                float2 v = sh[ci][ly + p][lx + q];
#pragma unroll
                for (int o = 0; o < COUT; o++) {
                    float wr = wsr[(o * CIN + ci) * 9 + p * 3 + q];
                    float wi = wsi[(o * CIN + ci) * 9 + p * 3 + q];
                    accr[o] += v.x * wr - v.y * wi;
                    acci[o] += v.x * wi + v.y * wr;
                }
            }
    if (WTM) {
        float wr = wtr[(size_t)b * MM + (size_t)y * 257 + x];
        float wi = wti[(size_t)b * MM + (size_t)y * 257 + x];
        float r0 = accr[0] * wr - acci[0] * wi;
        float i0 = accr[0] * wi + acci[0] * wr;
        accr[0] = r0; acci[0] = i0;
    }
    float2* ob = (float2*)out + (size_t)b * COUT * MM + (size_t)y * 257 + x;
#pragma unroll
    for (int o = 0; o < COUT; o++)
        ob[(size_t)o * MM] = make_float2(accr[o], acci[o]);
}

// --------------------------- norm reduction ---------------------------------
__global__ void k_reduce(const float* __restrict__ r, const float* __restrict__ fr,
                         const float* __restrict__ fi, float* __restrict__ acc) {
    int b = blockIdx.y;
    int tid = threadIdx.x;
    float sr = 0.f, sf = 0.f;
    for (int idx = blockIdx.x * 256 + tid; idx < NN; idx += gridDim.x * 256) {
        const float* rp = r + ((size_t)b * NN + idx) * 2;
        float rx = rp[0], ry = rp[1];
        sr += rx * rx + ry * ry;
        float a = fr[(size_t)b * NN + idx], c = fi[(size_t)b * NN + idx];
        sf += a * a + c * c;
    }
    for (int off = 32; off > 0; off >>= 1) {
        sr += __shfl_down(sr, off);
        sf += __shfl_down(sf, off);
    }
    __shared__ float ssr[4], ssf[4];
    int wid = tid >> 6, lane = tid & 63;
    if (lane == 0) { ssr[wid] = sr; ssf[wid] = sf; }
    __syncthreads();
    if (tid == 0) {
        float tr = ssr[0] + ssr[1] + ssr[2] + ssr[3];
        float tf = ssf[0] + ssf[1] + ssf[2] + ssf[3];
        atomicAdd(&acc[2 * b], tr);
        atomicAdd(&acc[2 * b + 1], tf);
    }
}

__global__ void k_finalize(const float* __restrict__ acc, float* __restrict__ out) {
    if (threadIdx.x == 0 && blockIdx.x == 0) {
        float num = 0.f, den = 0.f;
        for (int b = 0; b < BB; b++) {
            num += sqrtf(acc[2 * b]);
            den += sqrtf(acc[2 * b + 1]);
        }
        out[0] = num / den;
    }
}

// ---------------------------------------------------------------------------
extern "C" void kernel_launch(void* const* d_in, const int* in_sizes, int n_in,
                              void* d_out, int out_size, void* d_ws, size_t ws_size,
                              hipStream_t stream) {
    (void)in_sizes; (void)n_in; (void)out_size; (void)ws_size;
    const float* fr  = (const float*)d_in[0];
    const float* fi  = (const float*)d_in[1];
    const float* kap = (const float*)d_in[2];
    const float* w1r = (const float*)d_in[3];
    const float* w1i = (const float*)d_in[4];
    const float* w2r = (const float*)d_in[5];
    const float* w2i = (const float*)d_in[6];
    const float* w3r = (const float*)d_in[7];
    const float* w3i = (const float*)d_in[8];
    const float* wtr = (const float*)d_in[9];
    const float* wti = (const float*)d_in[10];
    const int K = 3;   // epoch=81 -> (81-1)/40+1

    float* ws = (float*)d_ws;
    size_t off = 0;
    float* x0   = ws + off; off += (size_t)BB * NN * 2;
    float* x1   = ws + off; off += (size_t)BB * NN * 2;
    float* rb   = ws + off; off += (size_t)BB * NN * 2;
    float* kap2 = ws + off; off += (size_t)BB * NN;
    float* dinv = ws + off; off += (size_t)BB * NN;
    float* tA   = ws + off; off += (size_t)BB * MM * 2;
    float* tB   = ws + off; off += (size_t)BB * MM * 2;
    float* c4a  = ws + off; off += (size_t)BB * 4 * MM * 2;
    float* c4b  = ws + off; off += (size_t)BB * 4 * MM * 2;
    float* S    = ws + off; off += 257 * 256;
    float* W    = ws + off; off += 256 * 257 * 2;
    float* acc  = ws + off; off += 16;
    // bf16 pack buffers (2B each, counts even -> 4B alignment preserved)
    unsigned short* us = (unsigned short*)(ws + off);
    size_t so = 0;
    unsigned short* sA1h = us + so; so += 129 * 512;
    unsigned short* sA1l = us + so; so += 129 * 512;
    unsigned short* sA2h = us + so; so += 129 * 512;
    unsigned short* sA2l = us + so; so += 129 * 512;
    unsigned short* wA1h = us + so; so += 256 * 544;
    unsigned short* wA1l = us + so; so += 256 * 544;
    unsigned short* wA2h = us + so; so += 256 * 544;
    unsigned short* wA2l = us + so; so += 256 * 544;
    unsigned short* wBh  = us + so; so += 256 * 544;
    unsigned short* wBl  = us + so; so += 256 * 544;
    const long dStrA = (long)257 * 544;
    unsigned short* dA1h = us + so; so += (size_t)BB * dStrA;
    unsigned short* dA1l = us + so; so += (size_t)BB * dStrA;
    unsigned short* dA2h = us + so; so += (size_t)BB * dStrA;
    unsigned short* dA2l = us + so; so += (size_t)BB * dStrA;
    unsigned short* dBh  = us + so; so += (size_t)BB * dStrA;
    unsigned short* dBl  = us + so; so += (size_t)BB * dStrA;

    int sgrid = (BB * NN + 255) / 256;
    k_init<<<sgrid, 256, 0, stream>>>(kap, kap2, dinv, x0, acc);
    k_mats<<<(257 * 257 + 255) / 256, 256, 0, stream>>>(S, W);
    k_packstat<<<(256 * 544 + 255) / 256, 256, 0, stream>>>(
        S, W, sA1h, sA1l, sA2h, sA2l, wA1h, wA1l, wA2h, wA2l, wBh, wBl);

    float* xc = x0;
    float* xo = x1;
    for (int it = 0; it < K; ++it) {
        for (int s = 0; s < 3; ++s) {
            k_step<<<sgrid, 256, 0, stream>>>(xc, xo, fr, fi, kap2, dinv, 0);
            float* t = xc; xc = xo; xo = t;
        }
        k_step<<<sgrid, 256, 0, stream>>>(xc, rb, fr, fi, kap2, dinv, 1);

        // DST1: tA[u<129][p<256] = sum_m S[u][m]*rb[m][p]
        k_packT<<<dim3(8, 8, BB), 256, 0, stream>>>(rb, 256, 256, 512,
            (long)NN, dBh, dBl, (long)256 * 512);
        mgemm<0><<<dim3(8, 5, BB), 256, 0, stream>>>(
            sA1h, sA1l, sA2h, sA2l, dBh, dBl, tA,
            129, 256, 512, 256, 0, (long)256 * 512, (long)MM, 1.f);

        // DST2 quadrant + mirror: tB = C1 * tA * S^T
        k_packS<<<dim3(129, 1, BB), 256, 0, stream>>>(tA, 129, 256, 256, 512,
            (long)MM * 2, dA1h, dA1l, dA2h, dA2l, (long)129 * 512);
        mgemm<2><<<dim3(5, 5, BB), 256, 0, stream>>>(
            dA1h, dA1l, dA2h, dA2l, sA1h, sA1l, tB,
            129, 129, 512, 257, (long)129 * 512, 0, (long)MM, C1F);

        // conv chain forward (+wt fused into third)
        k_convT<1, 4, 0, 0><<<dim3(297, BB), 256, 0, stream>>>(tB, c4b, w1r, w1i, fr, fi);
        k_convT<4, 4, 0, 0><<<dim3(297, BB), 256, 0, stream>>>(c4b, c4a, w2r, w2i, fr, fi);
        k_convT<4, 1, 0, 1><<<dim3(297, BB), 256, 0, stream>>>(c4a, tA, w3r, w3i, wtr, wti);
        // conv chain adjoint
        k_convT<1, 4, 1, 0><<<dim3(297, BB), 256, 0, stream>>>(tA, c4b, w3r, w3i, fr, fi);
        k_convT<4, 4, 1, 0><<<dim3(297, BB), 256, 0, stream>>>(c4b, c4a, w2r, w2i, fr, fi);
        k_convT<4, 1, 1, 0><<<dim3(297, BB), 256, 0, stream>>>(c4a, tA, w1r, w1i, fr, fi);

        // DFT1: tB[k<256][v<257] = sum_u W[k][u]*tA[u][v]
        k_packT<<<dim3(9, 9, BB), 256, 0, stream>>>(tA, 257, 257, 544,
            (long)MM, dBh, dBl, dStrA);
        mgemm<0><<<dim3(9, 8, BB), 256, 0, stream>>>(
            wA1h, wA1l, wA2h, wA2l, dBh, dBl, tB,
            256, 257, 544, 257, 0, dStrA, (long)MM, 1.f);

        // DFT2 + add: xc[k][l] += sum_v tB[k][v]*WT[v][l]
        k_packS<<<dim3(272, 1, BB), 256, 0, stream>>>(tB, 256, 257, 257, 544,
            (long)MM * 2, dA1h, dA1l, dA2h, dA2l, (long)256 * 544);
        mgemm<1><<<dim3(8, 8, BB), 256, 0, stream>>>(
            dA1h, dA1l, dA2h, dA2l, wBh, wBl, xc,
            256, 256, 544, 256, (long)256 * 544, 0, (long)NN, 1.f);
    }
    k_step<<<sgrid, 256, 0, stream>>>(xc, rb, fr, fi, kap2, dinv, 1);
    k_reduce<<<dim3(32, BB), 256, 0, stream>>>(rb, fr, fi, acc);
    k_finalize<<<1, 64, 0, stream>>>(acc, (float*)d_out);
}

// Round 7
// 557.793 us; speedup vs baseline: 2.6984x; 1.4019x over previous
//
#include <hip/hip_runtime.h>

// ---------------------------------------------------------------------------
// HyperFNS: Helmholtz Jacobi + FNS spectral correction, B=8, N=256, K=3.
// Transforms = MFMA complex GEMMs (bf16 split-precision, K-interleaved),
// A-pack fused into GEMM epilogue. Conv chain fully fused (1 kernel/chain).
// Jacobi steps fused in pairs via halo-2 LDS tiles.
// ---------------------------------------------------------------------------

#define BB 8
#define NN 65536          // 256*256
#define MM 66049          // 257*257

constexpr double PI_D    = 3.14159265358979323846;
constexpr double OMEGA_D = 40.0 * PI_D;
constexpr double H_D     = 1.0 / 255.0;
constexpr float  OMEGA2F = (float)(OMEGA_D * OMEGA_D);
constexpr float  BCVF    = (float)(2.0 * H_D * OMEGA_D);
constexpr float  INVH2F  = 65025.0f;
constexpr float  C1F     = (float)(-4.0 / (514.0 * 514.0));
constexpr float  TP514   = (float)(2.0 * PI_D / 514.0);

typedef __attribute__((ext_vector_type(8))) short short8v;
typedef __attribute__((ext_vector_type(8))) unsigned short us8;
typedef __attribute__((ext_vector_type(4))) float f32x4;

// --------------------------- bf16 split helpers -----------------------------
__device__ inline unsigned short bfh(float x) {
    unsigned u = __float_as_uint(x);
    unsigned r = (u + 0x7FFFu + ((u >> 16) & 1u)) >> 16;
    return (unsigned short)r;
}
__device__ inline float bfh_f(unsigned short h) {
    return __uint_as_float(((unsigned)h) << 16);
}
__device__ inline void bsplit(float x, unsigned short& h, unsigned short& l) {
    h = bfh(x);
    l = bfh(x - bfh_f(h));
}

// --------------------------- init -------------------------------------------
__global__ void k_init(const float* __restrict__ kappa, float* __restrict__ kap2,
                       float* __restrict__ dinv, float* __restrict__ x0,
                       float* __restrict__ acc) {
    int t = blockIdx.x * 256 + threadIdx.x;
    if (t < BB * NN) {
        float k = kappa[t];
        float k2 = k * k;
        kap2[t] = k2;
        dinv[t] = 1.0f / (4.0f * INVH2F - OMEGA2F * k2);
        x0[2 * t] = 0.f; x0[2 * t + 1] = 0.f;
    }
    if (t < 16) acc[t] = 0.f;
}

// --------------------------- transform matrices (fp32) ----------------------
__global__ void k_mats(float* __restrict__ S, float* __restrict__ W) {
    int t = blockIdx.x * 256 + threadIdx.x;
    if (t >= 257 * 257) return;
    int i = t / 257, j = t % 257;
    if (j < 256) {
        int a = (i - 128) * (j + 1);
        int m = ((a % 514) + 514) % 514;
        S[i * 256 + j] = sinf(m * TP514);
    }
    if (i < 256) {
        int tt = (i * (j + 129)) % 514;
        float cc = cosf(tt * TP514), ss = sinf(tt * TP514);
        float sg = (i & 1) ? -1.f : 1.f;
        W[(i * 257 + j) * 2] = sg * cc;
        W[(i * 257 + j) * 2 + 1] = -sg * ss;
    }
}

// --------------------------- static bf16 packs (KP=576 for W side) ----------
__global__ void k_packstat(const float* __restrict__ S, const float* __restrict__ W,
        unsigned short* sA1h, unsigned short* sA1l,
        unsigned short* sA2h, unsigned short* sA2l,
        unsigned short* wA1h, unsigned short* wA1l,
        unsigned short* wA2h, unsigned short* wA2l,
        unsigned short* wBh,  unsigned short* wBl) {
    int t = blockIdx.x * 256 + threadIdx.x;
    if (t >= 256 * 576) return;
    int i = t / 576, c = t % 576;
    {
        unsigned short h1 = 0, l1 = 0, h2 = 0, l2 = 0, hb = 0, lb = 0;
        if (c < 514) {
            int u = c >> 1;
            float wr = W[(i * 257 + u) * 2];
            float wi = W[(i * 257 + u) * 2 + 1];
            if ((c & 1) == 0) {
                bsplit(wr, h1, l1); bsplit(wi, h2, l2); bsplit(wr, hb, lb);
            } else {
                bsplit(-wi, h1, l1); bsplit(wr, h2, l2); bsplit(wi, hb, lb);
            }
        }
        size_t o = (size_t)i * 576 + c;
        wA1h[o] = h1; wA1l[o] = l1;
        wA2h[o] = h2; wA2l[o] = l2;
        wBh[o] = hb;  wBl[o] = lb;
    }
    if (i < 129 && c < 512) {
        int m = c >> 1;
        float s = S[i * 256 + m];
        unsigned short hs, ls;
        bsplit(s, hs, ls);
        size_t o = (size_t)i * 512 + c;
        if ((c & 1) == 0) { sA1h[o] = hs; sA1l[o] = ls; sA2h[o] = 0; sA2l[o] = 0; }
        else              { sA1h[o] = 0;  sA1l[o] = 0;  sA2h[o] = hs; sA2l[o] = ls; }
    }
}

// --------------------------- single stencil (final residual) ----------------
__global__ void k_step(const float* __restrict__ xin, float* __restrict__ out,
                       const float* __restrict__ fr, const float* __restrict__ fi,
                       const float* __restrict__ kap2) {
    int t = blockIdx.x * 256 + threadIdx.x;
    if (t >= BB * NN) return;
    int b = t >> 16;
    int ij = t & 65535;
    int i = ij >> 8, j = ij & 255;
    const float* xb = xin + (size_t)b * NN * 2;
    float xcr = xb[2 * ij], xci = xb[2 * ij + 1];
    float ur, ui, dr, di, lr, li, rr, ri;
    if (i > 0) { int n = ij - 256; ur = xb[2 * n]; ui = xb[2 * n + 1]; }
    else { int n = 256 + j; ur = xb[2 * n] - BCVF * xci; ui = xb[2 * n + 1] + BCVF * xcr; }
    if (i < 255) { int n = ij + 256; dr = xb[2 * n]; di = xb[2 * n + 1]; }
    else { int n = 254 * 256 + j; dr = xb[2 * n] - BCVF * xci; di = xb[2 * n + 1] + BCVF * xcr; }
    if (j > 0) { int n = ij - 1; lr = xb[2 * n]; li = xb[2 * n + 1]; }
    else { int n = i * 256 + 1; lr = xb[2 * n] - BCVF * xci; li = xb[2 * n + 1] + BCVF * xcr; }
    if (j < 255) { int n = ij + 1; rr = xb[2 * n]; ri = xb[2 * n + 1]; }
    else { int n = i * 256 + 254; rr = xb[2 * n] - BCVF * xci; ri = xb[2 * n + 1] + BCVF * xcr; }
    float k2 = kap2[t];
    float axr = (4.f * xcr - ur - dr - lr - rr) * INVH2F - OMEGA2F * k2 * xcr;
    float axi = (4.f * xci - ui - di - li - ri) * INVH2F - OMEGA2F * k2 * xci;
    out[2 * t] = fr[t] - axr;
    out[2 * t + 1] = fi[t] - axi;
}

// --------------------------- fused double stencil ---------------------------
// step1 = smooth on halo-1 region; step2 = smooth (RESID=0) or residual
// (RESID=1, also writes step1's x3 result to xout).
template<int RESID>
__global__ __launch_bounds__(256) void k_step2(
        const float* __restrict__ xin, float* __restrict__ xout, float* __restrict__ rb,
        const float* __restrict__ fr, const float* __restrict__ fi,
        const float* __restrict__ kap2, const float* __restrict__ dinv) {
    const int b = blockIdx.y;
    const int tx = blockIdx.x & 7, ty = blockIdx.x >> 3;
    const int x0 = tx * 32, y0 = ty * 8;
    __shared__ float2 xs[12][37];
    __shared__ float2 ys[10][35];
    __shared__ float2 fs[10][35];
    __shared__ float ks2[10][35], ds2[10][35];
    const int tid = threadIdx.x;
    const float2* xb = (const float2*)xin + (size_t)b * NN;
    for (int i = tid; i < 432; i += 256) {
        int r = i / 36, c = i % 36;
        int gy = y0 - 2 + r, gx = x0 - 2 + c;
        float2 v = make_float2(0.f, 0.f);
        if ((unsigned)gy < 256u && (unsigned)gx < 256u) v = xb[gy * 256 + gx];
        xs[r][c] = v;
    }
    for (int i = tid; i < 340; i += 256) {
        int r = i / 34, c = i % 34;
        int gy = y0 - 1 + r, gx = x0 - 1 + c;
        float2 fv = make_float2(0.f, 0.f); float kv = 0.f, dvv = 0.f;
        if ((unsigned)gy < 256u && (unsigned)gx < 256u) {
            size_t o = (size_t)b * NN + gy * 256 + gx;
            fv = make_float2(fr[o], fi[o]); kv = kap2[o]; dvv = dinv[o];
        }
        fs[r][c] = fv; ks2[r][c] = kv; ds2[r][c] = dvv;
    }
    __syncthreads();
    for (int i = tid; i < 340; i += 256) {
        int r = i / 34, c = i % 34;
        int gy = y0 - 1 + r, gx = x0 - 1 + c;
        float2 o = make_float2(0.f, 0.f);
        if ((unsigned)gy < 256u && (unsigned)gx < 256u) {
            int xr = r + 1, xc = c + 1;
            float2 ctr = xs[xr][xc];
            float2 up, dn, lf, rt;
            if (gy > 0) up = xs[xr - 1][xc];
            else { float2 n = xs[xr + 1][xc]; up = make_float2(n.x - BCVF * ctr.y, n.y + BCVF * ctr.x); }
            if (gy < 255) dn = xs[xr + 1][xc];
            else { float2 n = xs[xr - 1][xc]; dn = make_float2(n.x - BCVF * ctr.y, n.y + BCVF * ctr.x); }
            if (gx > 0) lf = xs[xr][xc - 1];
            else { float2 n = xs[xr][xc + 1]; lf = make_float2(n.x - BCVF * ctr.y, n.y + BCVF * ctr.x); }
            if (gx < 255) rt = xs[xr][xc + 1];
            else { float2 n = xs[xr][xc - 1]; rt = make_float2(n.x - BCVF * ctr.y, n.y + BCVF * ctr.x); }
            float k2 = ks2[r][c];
            float axr = (4.f * ctr.x - up.x - dn.x - lf.x - rt.x) * INVH2F - OMEGA2F * k2 * ctr.x;
            float axi = (4.f * ctr.y - up.y - dn.y - lf.y - rt.y) * INVH2F - OMEGA2F * k2 * ctr.y;
            float2 fv = fs[r][c];
            float dv = ds2[r][c] * (2.0f / 3.0f);
            o = make_float2(ctr.x + dv * (fv.x - axr), ctr.y + dv * (fv.y - axi));
        }
        ys[r][c] = o;
    }
    __syncthreads();
    const int lx = tid & 31, ly = tid >> 5;
    const int gy = y0 + ly, gx = x0 + lx;
    const int yr = ly + 1, yc = lx + 1;
    float2 ctr = ys[yr][yc];
    float2 up, dn, lf, rt;
    if (gy > 0) up = ys[yr - 1][yc];
    else { float2 n = ys[yr + 1][yc]; up = make_float2(n.x - BCVF * ctr.y, n.y + BCVF * ctr.x); }
    if (gy < 255) dn = ys[yr + 1][yc];
    else { float2 n = ys[yr - 1][yc]; dn = make_float2(n.x - BCVF * ctr.y, n.y + BCVF * ctr.x); }
    if (gx > 0) lf = ys[yr][yc - 1];
    else { float2 n = ys[yr][yc + 1]; lf = make_float2(n.x - BCVF * ctr.y, n.y + BCVF * ctr.x); }
    if (gx < 255) rt = ys[yr][yc + 1];
    else { float2 n = ys[yr][yc - 1]; rt = make_float2(n.x - BCVF * ctr.y, n.y + BCVF * ctr.x); }
    float k2 = ks2[yr][yc];
    float axr = (4.f * ctr.x - up.x - dn.x - lf.x - rt.x) * INVH2F - OMEGA2F * k2 * ctr.x;
    float axi = (4.f * ctr.y - up.y - dn.y - lf.y - rt.y) * INVH2F - OMEGA2F * k2 * ctr.y;
    float2 fv = fs[yr][yc];
    size_t t = (size_t)b * NN + gy * 256 + gx;
    if (!RESID) {
        float dv = ds2[yr][yc] * (2.0f / 3.0f);
        xout[2 * t] = ctr.x + dv * (fv.x - axr);
        xout[2 * t + 1] = ctr.y + dv * (fv.y - axi);
    } else {
        xout[2 * t] = ctr.x; xout[2 * t + 1] = ctr.y;
        rb[2 * t] = fv.x - axr; rb[2 * t + 1] = fv.y - axi;
    }
}

// --------------------------- data pack: transpose (B-side) ------------------
__global__ __launch_bounds__(256) void k_packT(
        const float* __restrict__ in, int Min, int Nin, int KP,
        long inStrF2, unsigned short* __restrict__ Bh, unsigned short* __restrict__ Bl,
        long outStr) {
    int b = blockIdx.z;
    int n0 = blockIdx.x * 32, u0 = blockIdx.y * 32;
    __shared__ float2 lds[32][33];
    int tid = threadIdx.x;
    int r = tid >> 5, c = tid & 31;
    const float2* ip = (const float2*)in + (size_t)b * inStrF2;
    for (int rr = r; rr < 32; rr += 8) {
        int u = u0 + rr, n = n0 + c;
        float2 v = make_float2(0.f, 0.f);
        if (u < Min && n < Nin) v = ip[(size_t)u * Nin + n];
        lds[rr][c] = v;
    }
    __syncthreads();
    int tn = tid >> 3, tu4 = (tid & 7) * 4;
    int n = n0 + tn;
    if (n >= Nin) return;
    if (u0 + tu4 + 4 > (KP >> 1)) return;
    unsigned short hs[8], ls[8];
#pragma unroll
    for (int j = 0; j < 4; j++) {
        float2 v = lds[tu4 + j][tn];
        bsplit(v.x, hs[2 * j], ls[2 * j]);
        bsplit(v.y, hs[2 * j + 1], ls[2 * j + 1]);
    }
    size_t o = (size_t)b * outStr + (size_t)n * KP + 2 * (u0 + tu4);
    *(ushort4*)&Bh[o]     = make_ushort4(hs[0], hs[1], hs[2], hs[3]);
    *(ushort4*)&Bh[o + 4] = make_ushort4(hs[4], hs[5], hs[6], hs[7]);
    *(ushort4*)&Bl[o]     = make_ushort4(ls[0], ls[1], ls[2], ls[3]);
    *(ushort4*)&Bl[o + 4] = make_ushort4(ls[4], ls[5], ls[6], ls[7]);
}

// --------------------------- MFMA complex GEMM ------------------------------
// EPI: 0 store C, 1 add into C, 2 mirror-store (odd sym 257x257, scale),
//      3 write next-GEMM A-pack (P1/P2 h,l) instead of C.
template<int EPI>
__global__ __launch_bounds__(256) void mgemm(
        const unsigned short* __restrict__ A1h, const unsigned short* __restrict__ A1l,
        const unsigned short* __restrict__ A2h, const unsigned short* __restrict__ A2l,
        const unsigned short* __restrict__ Bh,  const unsigned short* __restrict__ Bl,
        float* __restrict__ C,
        unsigned short* __restrict__ P1h, unsigned short* __restrict__ P1l,
        unsigned short* __restrict__ P2h, unsigned short* __restrict__ P2l,
        int M, int N, int KP, int ldc, int KPout,
        long aStr, long bStr, long cStrF2, long pStr, float scale) {
    constexpr int LR = 72;
    __shared__ unsigned short shA1h[32 * LR], shA1l[32 * LR];
    __shared__ unsigned short shA2h[32 * LR], shA2l[32 * LR];
    __shared__ unsigned short shBh[32 * LR], shBl[32 * LR];
    const int tid = threadIdx.x;
    const int b = blockIdx.z;
    const unsigned short* pA1h = A1h + (size_t)b * aStr;
    const unsigned short* pA1l = A1l + (size_t)b * aStr;
    const unsigned short* pA2h = A2h + (size_t)b * aStr;
    const unsigned short* pA2l = A2l + (size_t)b * aStr;
    const unsigned short* pBh  = Bh + (size_t)b * bStr;
    const unsigned short* pBl  = Bl + (size_t)b * bStr;
    const int m0 = blockIdx.y * 32, n0 = blockIdx.x * 32;
    const int wave = tid >> 6, lane = tid & 63;
    const int wm = wave >> 1, wn = wave & 1;
    const int srow = tid >> 3, scol = (tid & 7) * 8;

    f32x4 accr = {0.f, 0.f, 0.f, 0.f}, acci = {0.f, 0.f, 0.f, 0.f};
    const int nks = KP >> 6;
    for (int ks = 0; ks < nks; ks++) {
        const int kb = ks * 64;
        const int so = srow * LR + scol;
        {
            int gm = m0 + srow;
            if (gm < M) {
                size_t ao = (size_t)gm * KP + kb + scol;
                *(us8*)&shA1h[so] = *(const us8*)&pA1h[ao];
                *(us8*)&shA1l[so] = *(const us8*)&pA1l[ao];
                *(us8*)&shA2h[so] = *(const us8*)&pA2h[ao];
                *(us8*)&shA2l[so] = *(const us8*)&pA2l[ao];
            } else {
                us8 z = (us8)0;
                *(us8*)&shA1h[so] = z; *(us8*)&shA1l[so] = z;
                *(us8*)&shA2h[so] = z; *(us8*)&shA2l[so] = z;
            }
            int gn = n0 + srow;
            if (gn < N) {
                size_t bo = (size_t)gn * KP + kb + scol;
                *(us8*)&shBh[so] = *(const us8*)&pBh[bo];
                *(us8*)&shBl[so] = *(const us8*)&pBl[bo];
            } else {
                us8 z = (us8)0;
                *(us8*)&shBh[so] = z; *(us8*)&shBl[so] = z;
            }
        }
        __syncthreads();
#pragma unroll
        for (int half = 0; half < 2; half++) {
            const int ko = half * 32 + ((lane >> 4) << 3);
            const int ar = (wm * 16 + (lane & 15)) * LR + ko;
            const int br = (wn * 16 + (lane & 15)) * LR + ko;
            short8v a1h = *(const short8v*)&shA1h[ar];
            short8v a1l = *(const short8v*)&shA1l[ar];
            short8v a2h = *(const short8v*)&shA2h[ar];
            short8v a2l = *(const short8v*)&shA2l[ar];
            short8v bh  = *(const short8v*)&shBh[br];
            short8v bl  = *(const short8v*)&shBl[br];
            accr = __builtin_amdgcn_mfma_f32_16x16x32_bf16(a1h, bh, accr, 0, 0, 0);
            accr = __builtin_amdgcn_mfma_f32_16x16x32_bf16(a1l, bh, accr, 0, 0, 0);
            accr = __builtin_amdgcn_mfma_f32_16x16x32_bf16(a1h, bl, accr, 0, 0, 0);
            acci = __builtin_amdgcn_mfma_f32_16x16x32_bf16(a2h, bh, acci, 0, 0, 0);
            acci = __builtin_amdgcn_mfma_f32_16x16x32_bf16(a2l, bh, acci, 0, 0, 0);
            acci = __builtin_amdgcn_mfma_f32_16x16x32_bf16(a2h, bl, acci, 0, 0, 0);
        }
        __syncthreads();
    }
    const int col = n0 + wn * 16 + (lane & 15);
    const int rbase = m0 + wm * 16 + ((lane >> 4) << 2);
    if (EPI == 3) {
        unsigned short* q1h = P1h + (size_t)b * pStr;
        unsigned short* q1l = P1l + (size_t)b * pStr;
        unsigned short* q2h = P2h + (size_t)b * pStr;
        unsigned short* q2l = P2l + (size_t)b * pStr;
#pragma unroll
        for (int i = 0; i < 4; i++) {
            int row = rbase + i;
            if (row >= M || col >= N) continue;
            float vr = scale * accr[i], vi = scale * acci[i];
            unsigned short hr, lr2, hi2, li2;
            bsplit(vr, hr, lr2); bsplit(vi, hi2, li2);
            size_t o = (size_t)row * KPout + 2 * col;
            q1h[o] = hr;  q1h[o + 1] = hi2 ^ 0x8000;
            q1l[o] = lr2; q1l[o + 1] = li2 ^ 0x8000;
            q2h[o] = hi2; q2h[o + 1] = hr;
            q2l[o] = li2; q2l[o + 1] = lr2;
        }
    } else {
        float* Cb = C + (size_t)b * cStrF2 * 2;
#pragma unroll
        for (int i = 0; i < 4; i++) {
            int row = rbase + i;
            if (row >= M || col >= N) continue;
            float vr = scale * accr[i], vi = scale * acci[i];
            if (EPI == 2) {
                int mm = 256 - row, nm = 256 - col;
                Cb[((size_t)row * 257 + col) * 2] = vr;  Cb[((size_t)row * 257 + col) * 2 + 1] = vi;
                Cb[((size_t)mm * 257 + col) * 2] = -vr;  Cb[((size_t)mm * 257 + col) * 2 + 1] = -vi;
                Cb[((size_t)row * 257 + nm) * 2] = -vr;  Cb[((size_t)row * 257 + nm) * 2 + 1] = -vi;
                Cb[((size_t)mm * 257 + nm) * 2] = vr;    Cb[((size_t)mm * 257 + nm) * 2 + 1] = vi;
            } else {
                size_t o = ((size_t)row * ldc + col) * 2;
                if (EPI == 1) { Cb[o] += vr; Cb[o + 1] += vi; }
                else          { Cb[o] = vr;  Cb[o + 1] = vi; }
            }
        }
    }
}

// --------------------------- fused 3-conv chain (+wt) -----------------------
// ADJ=0: w1(1->4), w2(4->4), w3(4->1), then *wt (WTM).
// ADJ=1: w3^H(1->4), w2^H(4->4), w1^H(4->1).
// Zero-padding semantics: intermediates forced to 0 outside the 257x257 grid.
template<int ADJ, int WTM>
__global__ __launch_bounds__(256) void k_convChain(
        const float* __restrict__ in, float* __restrict__ out,
        const float* __restrict__ w1r, const float* __restrict__ w1i,
        const float* __restrict__ w2r, const float* __restrict__ w2i,
        const float* __restrict__ w3r, const float* __restrict__ w3i,
        const float* __restrict__ wtr, const float* __restrict__ wti) {
    const int b = blockIdx.y;
    const int bx = blockIdx.x % 9, by = blockIdx.x / 9;
    const int x0 = bx * 32, y0 = by * 8;
    __shared__ float2 sh0[14][39];
    __shared__ float2 i1[4][12][37];
    __shared__ float2 i2[4][10][35];
    __shared__ float wAr[36], wAi[36], wBr[144], wBi[144], wCr[36], wCi[36];
    const int tid = threadIdx.x;
    if (tid < 36) {
        int o = tid / 9, pq = tid % 9, p = pq / 3, q = pq % 3;
        if (!ADJ) { int idx = b * 36 + o * 9 + pq; wAr[tid] = w1r[idx]; wAi[tid] = w1i[idx]; }
        else      { int idx = b * 36 + o * 9 + q * 3 + p; wAr[tid] = w3r[idx]; wAi[tid] = -w3i[idx]; }
    } else if (tid < 180) {
        int j = tid - 36; int o = j / 36, ci = (j / 9) & 3, pq = j % 9, p = pq / 3, q = pq % 3;
        if (!ADJ) { int idx = b * 144 + (o * 4 + ci) * 9 + pq; wBr[j] = w2r[idx]; wBi[j] = w2i[idx]; }
        else      { int idx = b * 144 + (ci * 4 + o) * 9 + q * 3 + p; wBr[j] = w2r[idx]; wBi[j] = -w2i[idx]; }
    } else if (tid < 216) {
        int j = tid - 180; int ci = j / 9, pq = j % 9, p = pq / 3, q = pq % 3;
        if (!ADJ) { int idx = b * 36 + ci * 9 + pq; wCr[j] = w3r[idx]; wCi[j] = w3i[idx]; }
        else      { int idx = b * 36 + ci * 9 + q * 3 + p; wCr[j] = w1r[idx]; wCi[j] = -w1i[idx]; }
    }
    const float2* ipb = (const float2*)in + (size_t)b * MM;
    for (int i = tid; i < 14 * 38; i += 256) {
        int r = i / 38, c = i % 38;
        int gy = y0 - 3 + r, gx = x0 - 3 + c;
        float2 v = make_float2(0.f, 0.f);
        if ((unsigned)gy < 257u && (unsigned)gx < 257u) v = ipb[(size_t)gy * 257 + gx];
        sh0[r][c] = v;
    }
    __syncthreads();
    for (int i = tid; i < 1728; i += 256) {
        int ch = i / 432, rem = i % 432, r = rem / 36, c = rem % 36;
        int gy = y0 - 2 + r, gx = x0 - 2 + c;
        float ar = 0.f, ai = 0.f;
        if ((unsigned)gy < 257u && (unsigned)gx < 257u) {
#pragma unroll
            for (int p = 0; p < 3; p++)
#pragma unroll
                for (int q = 0; q < 3; q++) {
                    float2 v = sh0[r + p][c + q];
                    float wr = wAr[ch * 9 + p * 3 + q], wi = wAi[ch * 9 + p * 3 + q];
                    ar += v.x * wr - v.y * wi;
                    ai += v.x * wi + v.y * wr;
                }
        }
        i1[ch][r][c] = make_float2(ar, ai);
    }
    __syncthreads();
    for (int i = tid; i < 1360; i += 256) {
        int ch = i / 340, rem = i % 340, r = rem / 34, c = rem % 34;
        int gy = y0 - 1 + r, gx = x0 - 1 + c;
        float ar = 0.f, ai = 0.f;
        if ((unsigned)gy < 257u && (unsigned)gx < 257u) {
#pragma unroll
            for (int ci = 0; ci < 4; ci++)
#pragma unroll
                for (int p = 0; p < 3; p++)
#pragma unroll
                    for (int q = 0; q < 3; q++) {
                        float2 v = i1[ci][r + p][c + q];
                        float wr = wBr[(ch * 4 + ci) * 9 + p * 3 + q];
                        float wi = wBi[(ch * 4 + ci) * 9 + p * 3 + q];
                        ar += v.x * wr - v.y * wi;
                        ai += v.x * wi + v.y * wr;
                    }
        }
        i2[ch][r][c] = make_float2(ar, ai);
    }
    __syncthreads();
    const int lx = tid & 31, ly = tid >> 5;
    const int x = x0 + lx, y = y0 + ly;
    if (x >= 257 || y >= 257) return;
    float ar = 0.f, ai = 0.f;
#pragma unroll
    for (int ci = 0; ci < 4; ci++)
#pragma unroll
        for (int p = 0; p < 3; p++)
#pragma unroll
            for (int q = 0; q < 3; q++) {
                float2 v = i2[ci][ly + p][lx + q];
                float wr = wCr[ci * 9 + p * 3 + q], wi = wCi[ci * 9 + p * 3 + q];
                ar += v.x * wr - v.y * wi;
                ai += v.x * wi + v.y * wr;
            }
    if (WTM) {
        size_t wo = (size_t)b * MM + (size_t)y * 257 + x;
        float wr = wtr[wo], wi = wti[wo];
        float r0 = ar * wr - ai * wi;
        float i0 = ar * wi + ai * wr;
        ar = r0; ai = i0;
    }
    ((float2*)out)[(size_t)b * MM + (size_t)y * 257 + x] = make_float2(ar, ai);
}

// --------------------------- norm reduction ---------------------------------
__global__ void k_reduce(const float* __restrict__ r, const float* __restrict__ fr,
                         const float* __restrict__ fi, float* __restrict__ acc) {
    int b = blockIdx.y;
    int tid = threadIdx.x;
    float sr = 0.f, sf = 0.f;
    for (int idx = blockIdx.x * 256 + tid; idx < NN; idx += gridDim.x * 256) {
        const float* rp = r + ((size_t)b * NN + idx) * 2;
        float rx = rp[0], ry = rp[1];
        sr += rx * rx + ry * ry;
        float a = fr[(size_t)b * NN + idx], c = fi[(size_t)b * NN + idx];
        sf += a * a + c * c;
    }
    for (int off = 32; off > 0; off >>= 1) {
        sr += __shfl_down(sr, off);
        sf += __shfl_down(sf, off);
    }
    __shared__ float ssr[4], ssf[4];
    int wid = tid >> 6, lane = tid & 63;
    if (lane == 0) { ssr[wid] = sr; ssf[wid] = sf; }
    __syncthreads();
    if (tid == 0) {
        float tr = ssr[0] + ssr[1] + ssr[2] + ssr[3];
        float tf = ssf[0] + ssf[1] + ssf[2] + ssf[3];
        atomicAdd(&acc[2 * b], tr);
        atomicAdd(&acc[2 * b + 1], tf);
    }
}

__global__ void k_finalize(const float* __restrict__ acc, float* __restrict__ out) {
    if (threadIdx.x == 0 && blockIdx.x == 0) {
        float num = 0.f, den = 0.f;
        for (int b = 0; b < BB; b++) {
            num += sqrtf(acc[2 * b]);
            den += sqrtf(acc[2 * b + 1]);
        }
        out[0] = num / den;
    }
}

// ---------------------------------------------------------------------------
extern "C" void kernel_launch(void* const* d_in, const int* in_sizes, int n_in,
                              void* d_out, int out_size, void* d_ws, size_t ws_size,
                              hipStream_t stream) {
    (void)in_sizes; (void)n_in; (void)out_size; (void)ws_size;
    const float* fr  = (const float*)d_in[0];
    const float* fi  = (const float*)d_in[1];
    const float* kap = (const float*)d_in[2];
    const float* w1r = (const float*)d_in[3];
    const float* w1i = (const float*)d_in[4];
    const float* w2r = (const float*)d_in[5];
    const float* w2i = (const float*)d_in[6];
    const float* w3r = (const float*)d_in[7];
    const float* w3i = (const float*)d_in[8];
    const float* wtr = (const float*)d_in[9];
    const float* wti = (const float*)d_in[10];
    const int K = 3;   // epoch=81 -> (81-1)/40+1

    float* ws = (float*)d_ws;
    size_t off = 0;
    float* x0   = ws + off; off += (size_t)BB * NN * 2;
    float* x1   = ws + off; off += (size_t)BB * NN * 2;
    float* x2   = ws + off; off += (size_t)BB * NN * 2;
    float* rb   = ws + off; off += (size_t)BB * NN * 2;
    float* kap2 = ws + off; off += (size_t)BB * NN;
    float* dinv = ws + off; off += (size_t)BB * NN;
    float* tA   = ws + off; off += (size_t)BB * MM * 2;
    float* tB   = ws + off; off += (size_t)BB * MM * 2;
    float* u1   = ws + off; off += (size_t)BB * MM * 2;
    float* S    = ws + off; off += 257 * 256;
    float* W    = ws + off; off += 256 * 257 * 2;
    float* acc  = ws + off; off += 16;

    unsigned short* us = (unsigned short*)(ws + off);
    size_t so = 0;
    unsigned short* sA1h = us + so; so += 129 * 512;
    unsigned short* sA1l = us + so; so += 129 * 512;
    unsigned short* sA2h = us + so; so += 129 * 512;
    unsigned short* sA2l = us + so; so += 129 * 512;
    unsigned short* wA1h = us + so; so += 256 * 576;
    unsigned short* wA1l = us + so; so += 256 * 576;
    unsigned short* wA2h = us + so; so += 256 * 576;
    unsigned short* wA2l = us + so; so += 256 * 576;
    unsigned short* wBh  = us + so; so += 256 * 576;
    unsigned short* wBl  = us + so; so += 256 * 576;
    const long DSASTR = (long)129 * 512;
    unsigned short* dsA1h = us + so; so += (size_t)BB * DSASTR;
    unsigned short* dsA1l = us + so; so += (size_t)BB * DSASTR;
    unsigned short* dsA2h = us + so; so += (size_t)BB * DSASTR;
    unsigned short* dsA2l = us + so; so += (size_t)BB * DSASTR;
    const long DFASTR = (long)256 * 576;
    unsigned short* dfA1h = us + so; so += (size_t)BB * DFASTR;
    unsigned short* dfA1l = us + so; so += (size_t)BB * DFASTR;
    unsigned short* dfA2h = us + so; so += (size_t)BB * DFASTR;
    unsigned short* dfA2l = us + so; so += (size_t)BB * DFASTR;
    const long DBSTR = (long)257 * 576;
    unsigned short* dBh  = us + so; so += (size_t)BB * DBSTR;
    unsigned short* dBl  = us + so; so += (size_t)BB * DBSTR;

    int sgrid = (BB * NN + 255) / 256;
    k_init<<<sgrid, 256, 0, stream>>>(kap, kap2, dinv, x0, acc);
    k_mats<<<(257 * 257 + 255) / 256, 256, 0, stream>>>(S, W);
    k_packstat<<<(256 * 576 + 255) / 256, 256, 0, stream>>>(
        S, W, sA1h, sA1l, sA2h, sA2l, wA1h, wA1l, wA2h, wA2l, wBh, wBl);

    float* xc = x0;
    for (int it = 0; it < K; ++it) {
        float* xn = (xc == x0) ? x2 : x0;
        k_step2<0><<<dim3(256, BB), 256, 0, stream>>>(xc, x1, rb, fr, fi, kap2, dinv);
        k_step2<1><<<dim3(256, BB), 256, 0, stream>>>(x1, xn, rb, fr, fi, kap2, dinv);

        // DST1: pack rb^T, then T[u<129][p<256] = S*rb, epilogue -> dsA pack
        k_packT<<<dim3(8, 8, BB), 256, 0, stream>>>(rb, 256, 256, 512,
            (long)NN, dBh, dBl, DBSTR);
        mgemm<3><<<dim3(8, 5, BB), 256, 0, stream>>>(
            sA1h, sA1l, sA2h, sA2l, dBh, dBl, nullptr,
            dsA1h, dsA1l, dsA2h, dsA2l,
            129, 256, 512, 0, 512, 0, DBSTR, 0, DSASTR, 1.f);
        // DST2 quadrant + mirror -> tB (257x257)
        mgemm<2><<<dim3(5, 5, BB), 256, 0, stream>>>(
            dsA1h, dsA1l, dsA2h, dsA2l, sA1h, sA1l, tB,
            nullptr, nullptr, nullptr, nullptr,
            129, 129, 512, 257, 0, DSASTR, 0, (long)MM, 0, C1F);

        // conv chains (forward +wt, adjoint)
        k_convChain<0, 1><<<dim3(297, BB), 256, 0, stream>>>(
            tB, u1, w1r, w1i, w2r, w2i, w3r, w3i, wtr, wti);
        k_convChain<1, 0><<<dim3(297, BB), 256, 0, stream>>>(
            u1, tA, w1r, w1i, w2r, w2i, w3r, w3i, wtr, wti);

        // DFT1: pack tA^T, then G[k<256][v<257] = W*tA, epilogue -> dfA pack
        k_packT<<<dim3(9, 9, BB), 256, 0, stream>>>(tA, 257, 257, 576,
            (long)MM, dBh, dBl, DBSTR);
        mgemm<3><<<dim3(9, 8, BB), 256, 0, stream>>>(
            wA1h, wA1l, wA2h, wA2l, dBh, dBl, nullptr,
            dfA1h, dfA1l, dfA2h, dfA2l,
            256, 257, 576, 0, 576, 0, DBSTR, 0, DFASTR, 1.f);
        // DFT2 + add into xn
        mgemm<1><<<dim3(8, 8, BB), 256, 0, stream>>>(
            dfA1h, dfA1l, dfA2h, dfA2l, wBh, wBl, xn,
            nullptr, nullptr, nullptr, nullptr,
            256, 256, 576, 256, 0, DFASTR, 0, (long)NN, 0, 1.f);
        xc = xn;
    }
    k_step<<<sgrid, 256, 0, stream>>>(xc, rb, fr, fi, kap2);
    k_reduce<<<dim3(32, BB), 256, 0, stream>>>(rb, fr, fi, acc);
    k_finalize<<<1, 64, 0, stream>>>(acc, (float*)d_out);
}